// Round 6
// baseline (775.046 us; speedup 1.0000x reference)
//
#include <hip/hip_runtime.h>

// Problem constants
#define TP 512   // passage length
#define TB 8     // batch
#define TD 256   // input size
#define TH 75    // attn hidden
#define THP 80   // padded attn hidden (float4-friendly, pads zeroed)
#define TO 128   // GRU hidden

typedef _Float16 half_t;
typedef _Float16 half4v __attribute__((ext_vector_type(4)));
typedef _Float16 half8v __attribute__((ext_vector_type(8)));
typedef float    float4v __attribute__((ext_vector_type(4)));

__device__ __forceinline__ float fast_rcp(float x) { return __builtin_amdgcn_rcpf(x); }
__device__ __forceinline__ float fast_tanh(float x) {
    return 1.0f - 2.0f * fast_rcp(1.0f + __expf(2.0f * x));
}
__device__ __forceinline__ float fast_sigmoid(float x) {
    return fast_rcp(1.0f + __expf(-x));
}
__device__ __forceinline__ float f4c(const float4 a, int u) {
    return (u == 0) ? a.x : (u == 1) ? a.y : (u == 2) ? a.z : a.w;
}
// score partial: sum c * rcp(1+exp(2(a+b)));  tanh(x) = 1 - 2*rcp(1+exp(2x))
__device__ __forceinline__ float rterm4(float4 a, float4 b, float4 c) {
    float s;
    s  = c.x * fast_rcp(1.0f + __expf(2.0f * (a.x + b.x)));
    s += c.y * fast_rcp(1.0f + __expf(2.0f * (a.y + b.y)));
    s += c.z * fast_rcp(1.0f + __expf(2.0f * (a.z + b.z)));
    s += c.w * fast_rcp(1.0f + __expf(2.0f * (a.w + b.w)));
    return s;
}

// ---------------- prep: f16 casts + B-fragment / A-fragment swizzles --------
// B-frag layout (mfma_f32_16x16x32_f16): [nt][kt][lane][j] halfs with
// B[k = kt*32 + (lane>>4)*8 + j][n = nt*16 + (lane&15)]  (verified R5 gatexp).
// A-frag wfrag: [dir][tile=g*8+m][kt][lane][j], A[m16=lane&15][k=(lane>>4)*8+j]
// (verified R4 gru).
__global__ __launch_bounds__(256) void prep_kernel(
    const float* __restrict__ v,
    const float* __restrict__ Wvp1, const float* __restrict__ Wvp2,
    const float* __restrict__ Wg,   const float* __restrict__ wihf,
    const float* __restrict__ wihb, const float* __restrict__ bihf,
    const float* __restrict__ bihb, const float* __restrict__ whhf,
    const float* __restrict__ whhb,
    float* __restrict__ bihC,
    half_t* __restrict__ v16, half_t* __restrict__ Wg16B,
    half_t* __restrict__ Wih16B, half_t* __restrict__ wfrag,
    half_t* __restrict__ WT16B)
{
    int idx = blockIdx.x * 256 + threadIdx.x;
    if (idx < 1048576) {                        // v16 = (f16)v, same layout
        v16[idx] = (half_t)v[idx];
        return;
    }
    idx -= 1048576;
    if (idx < 768) { bihC[idx] = (idx < 384) ? bihf[idx] : bihb[idx - 384]; return; }
    idx -= 768;
    if (idx < 262144) {                         // Wg16B (nt 0..31)
        int j = idx & 7, lane = (idx >> 3) & 63, kt = (idx >> 9) & 15, nt = idx >> 13;
        int o = nt * 16 + (lane & 15);
        int k = kt * 32 + ((lane >> 4) << 3) + j;
        Wg16B[idx] = (half_t)Wg[o * 512 + k];
        return;
    }
    idx -= 262144;
    if (idx < 393216) {                         // Wih16B (nt 0..47, o<384 fwd)
        int j = idx & 7, lane = (idx >> 3) & 63, kt = (idx >> 9) & 15, nt = idx >> 13;
        int o = nt * 16 + (lane & 15);
        int k = kt * 32 + ((lane >> 4) << 3) + j;
        Wih16B[idx] = (half_t)((o < 384) ? wihf[o * 512 + k] : wihb[(o - 384) * 512 + k]);
        return;
    }
    idx -= 393216;
    if (idx < 98304) {                          // wfrag A-frags of w_hh
        int d    = idx / 49152;
        int r    = idx - d * 49152;
        int tile = r >> 11;
        int rem  = r & 2047;
        int kt   = rem >> 9;
        int rem2 = rem & 511;
        int lane = rem2 >> 3;
        int j    = rem2 & 7;
        int g = tile >> 3, m = tile & 7;
        int row = g * 128 + m * 16 + (lane & 15);
        int k   = kt * 32 + (lane >> 4) * 8 + j;
        const float* src = d ? whhb : whhf;
        wfrag[idx] = (half_t)src[row * TO + k];
        return;
    }
    idx -= 98304;
    if (idx < 40960) {                          // WT16B (nt 0..9): [Wvp1;Wvp2]
        int j = idx & 7, lane = (idx >> 3) & 63, kt = (idx >> 6) & 7, nt = idx >> 12;
        kt = (idx >> 9) & 7;                     // fix: kt is bits 9..11
        int o = nt * 16 + (lane & 15);
        int k = kt * 32 + ((lane >> 4) << 3) + j;
        float vv = 0.0f;
        if (o < 75)       vv = Wvp1[o * 256 + k];
        else if (o < 150) vv = Wvp2[(o - 75) * 256 + k];
        WT16B[idx] = (half_t)vv;
    }
}

// ---------------- Wv1/Wv2 via MFMA: [4096,160] = v16 @ WT16B ----------------
// 64 blocks x 256 thr (4 waves). Wave w owns m-tile w (16 rows), all 10 nt.
// A-frags loaded straight from global v16 (contiguous 16B per lane).
__global__ __launch_bounds__(256) void wv12_kernel(
    const half_t* __restrict__ v16, const half_t* __restrict__ WT16B,
    float* __restrict__ Wv1, float* __restrict__ Wv2)
{
    int tid = threadIdx.x;
    int lane = tid & 63, w = tid >> 6;
    int l15 = lane & 15, quad = lane >> 4;
    int r0 = blockIdx.x * 64 + w * 16;

    float4v acc[10];
#pragma unroll
    for (int nt = 0; nt < 10; ++nt) acc[nt] = (float4v){0.f, 0.f, 0.f, 0.f};

#pragma unroll
    for (int kt = 0; kt < 8; ++kt) {
        half8v a = *(const half8v*)(v16 + (r0 + l15) * 256 + kt * 32 + quad * 8);
#pragma unroll
        for (int nt = 0; nt < 10; ++nt) {
            half8v b = *(const half8v*)(WT16B + ((nt * 8 + kt) * 64 + lane) * 8);
            acc[nt] = __builtin_amdgcn_mfma_f32_16x16x32_f16(a, b, acc[nt], 0, 0, 0);
        }
    }
    // C/D: col = nt*16 + l15, row = r0 + quad*4 + r; rows are (p*8+b)
#pragma unroll
    for (int nt = 0; nt < 10; ++nt) {
        int col = nt * 16 + l15;
#pragma unroll
        for (int r = 0; r < 4; ++r) {
            int row = r0 + quad * 4 + r;
            int ob = ((row & 7) * TP + (row >> 3)) * THP;
            float val = acc[nt][r];
            if (col < 75)       Wv1[ob + col] = val;
            else if (col < 80)  { Wv2[ob + col - 75] = val; Wv1[ob + col] = 0.0f; }
            else if (col < 150) Wv2[ob + col - 75] = val;
            else if (col < 155) Wv2[ob + col - 75] = 0.0f;   // Wv2 pads
        }
    }
}

// -------- fused scores -> softmax(i) -> context -> build g16=[v,c] (f16) ----
__global__ __launch_bounds__(256) void attn_kernel(
    const float* __restrict__ v,
    const float* __restrict__ Wv1, const float* __restrict__ Wv2,
    const float* __restrict__ vw, half_t* __restrict__ g16)
{
    int tid = threadIdx.x;
    int b  = blockIdx.x >> 7;
    int j0 = (blockIdx.x & 127) * 4;
    __shared__ float wv1j[4 * THP];
    __shared__ float vws[THP];
    __shared__ float sc[4 * TP];

    if (tid < THP) vws[tid] = (tid < TH) ? vw[tid] : 0.0f;
    for (int e = tid; e < 4 * THP; e += 256) {
        int jj = e / THP, k = e - jj * THP;
        wv1j[e] = Wv1[(b * TP + j0 + jj) * THP + k];
    }
    __syncthreads();

    float Csum = 0.0f;
    {
        const float4* c4 = (const float4*)vws;
        for (int kk = 0; kk < 20; ++kk) { float4 c = c4[kk]; Csum += c.x + c.y + c.z + c.w; }
    }

    for (int rep = 0; rep < 2; ++rep) {
        int i = tid + rep * 256;
        const float4* row4 = (const float4*)(Wv2 + (b * TP + i) * THP);
        float acc[4] = {0.f, 0.f, 0.f, 0.f};
#pragma unroll
        for (int kt = 0; kt < 5; ++kt) {
            float4 r0 = row4[kt * 4 + 0], r1 = row4[kt * 4 + 1];
            float4 r2 = row4[kt * 4 + 2], r3 = row4[kt * 4 + 3];
            const float4* c4 = (const float4*)(vws + kt * 16);
            float4 c0 = c4[0], c1 = c4[1], c2 = c4[2], c3 = c4[3];
#pragma unroll
            for (int jj = 0; jj < 4; ++jj) {
                const float4* w1 = (const float4*)(wv1j + jj * THP + kt * 16);
                acc[jj] += rterm4(r0, w1[0], c0) + rterm4(r1, w1[1], c1)
                         + rterm4(r2, w1[2], c2) + rterm4(r3, w1[3], c3);
            }
        }
#pragma unroll
        for (int jj = 0; jj < 4; ++jj) sc[jj * TP + i] = Csum - 2.0f * acc[jj];
    }
    __syncthreads();

    {
        int jj = tid >> 6, l = tid & 63;
        float m = -1e30f;
#pragma unroll
        for (int q = 0; q < 8; ++q) m = fmaxf(m, sc[jj * TP + l + q * 64]);
#pragma unroll
        for (int s = 32; s > 0; s >>= 1) m = fmaxf(m, __shfl_xor(m, s));
        float e[8];
        float sum = 0.0f;
#pragma unroll
        for (int q = 0; q < 8; ++q) { e[q] = __expf(sc[jj * TP + l + q * 64] - m); sum += e[q]; }
#pragma unroll
        for (int s = 32; s > 0; s >>= 1) sum += __shfl_xor(sum, s);
        float inv = fast_rcp(sum);
#pragma unroll
        for (int q = 0; q < 8; ++q) sc[jj * TP + l + q * 64] = e[q] * inv;
    }
    __syncthreads();

    float acc[4] = {0.f, 0.f, 0.f, 0.f};
    const float* vb = v + b * TD + tid;
    for (int i4 = 0; i4 < TP / 4; ++i4) {
        float4 a0 = ((const float4*)(sc + 0 * TP))[i4];
        float4 a1 = ((const float4*)(sc + 1 * TP))[i4];
        float4 a2 = ((const float4*)(sc + 2 * TP))[i4];
        float4 a3 = ((const float4*)(sc + 3 * TP))[i4];
#pragma unroll
        for (int u = 0; u < 4; ++u) {
            float va = vb[(i4 * 4 + u) * (TB * TD)];
            acc[0] += f4c(a0, u) * va;
            acc[1] += f4c(a1, u) * va;
            acc[2] += f4c(a2, u) * va;
            acc[3] += f4c(a3, u) * va;
        }
    }
#pragma unroll
    for (int jj = 0; jj < 4; ++jj) {
        int base = ((j0 + jj) * TB + b) * 512;
        g16[base + tid]       = (half_t)v[((j0 + jj) * TB + b) * TD + tid];
        g16[base + 256 + tid] = (half_t)acc[jj];
    }
}

// -------- MFMA gate (sigmoid(g Wg^T)*g) + GRU input projections -------------
__global__ __launch_bounds__(256, 1) void gatexp_kernel(
    const half_t* __restrict__ g16, const half_t* __restrict__ Wg16B,
    const half_t* __restrict__ Wih16B, const float* __restrict__ bihC,
    float* __restrict__ xpf, float* __restrict__ xpb)
{
    __shared__ half_t gA[32 * 520];      // rows padded to 520 halfs
    int tid = threadIdx.x;
    int r0 = blockIdx.x * 32;
    int lane = tid & 63, w = tid >> 6;
    int l15 = lane & 15, quad = lane >> 4;

    for (int e = tid; e < 2048; e += 256) {
        int row = e >> 6, c8 = e & 63;
        *(half8v*)(gA + row * 520 + c8 * 8) =
            *(const half8v*)(g16 + (r0 + row) * 512 + c8 * 8);
    }
    __syncthreads();

    float4v acc[2][8];
#pragma unroll
    for (int mi = 0; mi < 2; ++mi)
#pragma unroll
        for (int nti = 0; nti < 8; ++nti) acc[mi][nti] = (float4v){0.f, 0.f, 0.f, 0.f};

    for (int kt = 0; kt < 16; ++kt) {
        half8v a0 = *(const half8v*)(gA + l15 * 520 + kt * 32 + quad * 8);
        half8v a1 = *(const half8v*)(gA + (16 + l15) * 520 + kt * 32 + quad * 8);
#pragma unroll
        for (int nti = 0; nti < 8; ++nti) {
            half8v bb = *(const half8v*)(Wg16B + (((w * 8 + nti) * 16 + kt) * 64 + lane) * 8);
            acc[0][nti] = __builtin_amdgcn_mfma_f32_16x16x32_f16(a0, bb, acc[0][nti], 0, 0, 0);
            acc[1][nti] = __builtin_amdgcn_mfma_f32_16x16x32_f16(a1, bb, acc[1][nti], 0, 0, 0);
        }
    }
#pragma unroll
    for (int mi = 0; mi < 2; ++mi)
#pragma unroll
        for (int nti = 0; nti < 8; ++nti) {
            int colg = (w * 8 + nti) * 16 + l15;
#pragma unroll
            for (int r = 0; r < 4; ++r) {
                float gv = (float)gA[(mi * 16 + quad * 4 + r) * 520 + colg];
                acc[mi][nti][r] = fast_sigmoid(acc[mi][nti][r]) * gv;
            }
        }
    __syncthreads();
#pragma unroll
    for (int mi = 0; mi < 2; ++mi)
#pragma unroll
        for (int nti = 0; nti < 8; ++nti) {
            int colg = (w * 8 + nti) * 16 + l15;
#pragma unroll
            for (int r = 0; r < 4; ++r)
                gA[(mi * 16 + quad * 4 + r) * 520 + colg] = (half_t)acc[mi][nti][r];
        }
    __syncthreads();

    float4v c2[2][12];
#pragma unroll
    for (int mi = 0; mi < 2; ++mi)
#pragma unroll
        for (int nt2 = 0; nt2 < 12; ++nt2) {
            float bv = bihC[(w * 12 + nt2) * 16 + l15];
            c2[mi][nt2] = (float4v){bv, bv, bv, bv};
        }

    for (int kt = 0; kt < 16; ++kt) {
        half8v a0 = *(const half8v*)(gA + l15 * 520 + kt * 32 + quad * 8);
        half8v a1 = *(const half8v*)(gA + (16 + l15) * 520 + kt * 32 + quad * 8);
#pragma unroll
        for (int nt2 = 0; nt2 < 12; ++nt2) {
            half8v bb = *(const half8v*)(Wih16B + (((w * 12 + nt2) * 16 + kt) * 64 + lane) * 8);
            c2[0][nt2] = __builtin_amdgcn_mfma_f32_16x16x32_f16(a0, bb, c2[0][nt2], 0, 0, 0);
            c2[1][nt2] = __builtin_amdgcn_mfma_f32_16x16x32_f16(a1, bb, c2[1][nt2], 0, 0, 0);
        }
    }
#pragma unroll
    for (int mi = 0; mi < 2; ++mi)
#pragma unroll
        for (int nt2 = 0; nt2 < 12; ++nt2) {
            int col = (w * 12 + nt2) * 16 + l15;
            float* dst = (col < 384) ? (xpf + col) : (xpb + col - 384);
#pragma unroll
            for (int r = 0; r < 4; ++r)
                dst[(r0 + mi * 16 + quad * 4 + r) * 384] = c2[mi][nt2][r];
        }
}

// ---------------- GRU recurrence: MFMA, one block per dir -------------------
// 512 thr = 8 waves. Wave w owns output rows [w*16, w*16+16) for all 3 gates
// (tiles g*8+w). Per step: gh(384x8) = W @ H via 12 MFMA/wave; C/D layout
// gives lane (n=batch, quad) rows w*16+quad*4..+3 for r,z,n in-register.
// Raw s_barrier with lgkmcnt-only wait: global out-stores / xp prefetch are
// NOT drained at the barrier (the R4 mistake). xp prefetch distance 1.
__global__ __launch_bounds__(512) void gru_kernel(
    const float* __restrict__ xpf, const float* __restrict__ xpb,
    const half_t* __restrict__ wfrag,
    const float* __restrict__ bhhf, const float* __restrict__ bhhb,
    float* __restrict__ out)
{
    int tid  = threadIdx.x;
    int dir  = blockIdx.x;
    int lane = tid & 63;
    int w    = tid >> 6;
    int n    = lane & 15;       // batch (valid < 8)
    int quad = lane >> 4;
    int row0 = w * 16 + quad * 4;

    const float* xp  = dir ? xpb  : xpf;
    const float* bhh = dir ? bhhb : bhhf;
    float* outp = out + dir * TO;

    __shared__ __align__(16) half_t Hb[2 * 2176];   // [buf][n*136 + k]

    half8v wf[3][4];
#pragma unroll
    for (int g = 0; g < 3; ++g) {
        int tile = g * 8 + w;
#pragma unroll
        for (int kt = 0; kt < 4; ++kt)
            wf[g][kt] = *(const half8v*)(
                wfrag + (((dir * 24 + tile) * 4 + kt) * 64 + lane) * 8);
    }

    float4v bias4[3];
#pragma unroll
    for (int g = 0; g < 3; ++g) {
        float4v bv;
#pragma unroll
        for (int r = 0; r < 4; ++r) bv[r] = bhh[g * 128 + row0 + r];
        bias4[g] = bv;
    }

    float hprev[4] = {0.f, 0.f, 0.f, 0.f};
    for (int i = tid; i < 2 * 2176; i += 512) Hb[i] = (half_t)0.0f;

    float4v xA[3], xB[3];
    {
        int t0 = dir ? (TP - 1) : 0;
        if (n < TB) {
#pragma unroll
            for (int g = 0; g < 3; ++g)
                xA[g] = *(const float4v*)(xp + (t0 * TB + n) * 384 + g * 128 + row0);
        }
    }
    __syncthreads();

#define GRU_STEP(S, RD, WRb, XU, XPF) do {                                     \
    int t_  = dir ? (TP - 1 - (S)) : (S);                                      \
    int sp_ = ((S) + 1 < TP) ? (S) + 1 : (S);                                  \
    int tp_ = dir ? (TP - 1 - sp_) : sp_;                                      \
    if (n < TB) {                                                              \
        _Pragma("unroll") for (int g = 0; g < 3; ++g)                          \
            XPF[g] = *(const float4v*)(                                        \
                xp + (tp_ * TB + n) * 384 + g * 128 + row0);                   \
    }                                                                          \
    half8v hf_[4];                                                             \
    _Pragma("unroll") for (int kt = 0; kt < 4; ++kt)                           \
        hf_[kt] = *(const half8v*)(Hb + (RD) * 2176 + n * 136 + kt * 32 + quad * 8); \
    float4v c_[3];                                                             \
    _Pragma("unroll") for (int g = 0; g < 3; ++g) c_[g] = bias4[g];            \
    _Pragma("unroll") for (int g = 0; g < 3; ++g)                              \
    _Pragma("unroll") for (int kt = 0; kt < 4; ++kt)                           \
        c_[g] = __builtin_amdgcn_mfma_f32_16x16x32_f16(wf[g][kt], hf_[kt], c_[g], 0, 0, 0); \
    if (n < TB) {                                                              \
        float4v hnew; half4v h16;                                              \
        _Pragma("unroll") for (int r = 0; r < 4; ++r) {                        \
            float rr = fast_sigmoid(XU[0][r] + c_[0][r]);                      \
            float zz = fast_sigmoid(XU[1][r] + c_[1][r]);                      \
            float nn = fast_tanh(XU[2][r] + rr * c_[2][r]);                    \
            float hv = (1.0f - zz) * nn + zz * hprev[r];                       \
            hprev[r] = hv; hnew[r] = hv; h16[r] = (half_t)hv;                  \
        }                                                                      \
        *(half4v*)(Hb + (WRb) * 2176 + n * 136 + row0) = h16;                  \
        *(float4v*)(outp + (t_ * TB + n) * 256 + row0) = hnew;                 \
    }                                                                          \
    asm volatile("s_waitcnt lgkmcnt(0)\n\ts_barrier" ::: "memory");            \
} while (0)

    for (int s = 0; s < TP; s += 2) {
        GRU_STEP(s,     0, 1, xA, xB);
        GRU_STEP(s + 1, 1, 0, xB, xA);
    }
#undef GRU_STEP
}

extern "C" void kernel_launch(void* const* d_in, const int* in_sizes, int n_in,
                              void* d_out, int out_size, void* d_ws, size_t ws_size,
                              hipStream_t stream) {
    const float* v    = (const float*)d_in[0];
    const float* Wvp1 = (const float*)d_in[1];
    const float* Wvp2 = (const float*)d_in[2];
    const float* vw   = (const float*)d_in[3];
    const float* Wg   = (const float*)d_in[4];
    const float* wihf = (const float*)d_in[5];
    const float* whhf = (const float*)d_in[6];
    const float* bihf = (const float*)d_in[7];
    const float* bhhf = (const float*)d_in[8];
    const float* wihb = (const float*)d_in[9];
    const float* whhb = (const float*)d_in[10];
    const float* bihb = (const float*)d_in[11];
    const float* bhhb = (const float*)d_in[12];

    float* ws   = (float*)d_ws;
    float* bihC = ws;                    // 768 f32
    float* Wv1  = bihC + 768;            // 8*512*80 = 327680
    float* Wv2  = Wv1 + 327680;          // 327680
    float* xpf  = Wv2 + 327680;          // 4096*384 = 1572864
    float* xpb  = xpf + 1572864;         // 1572864
    half_t* g16    = (half_t*)(xpb + 1572864);  // 4096*512   = 2097152 halfs
    half_t* Wg16B  = g16 + 2097152;             // 32*16*64*8 = 262144
    half_t* Wih16B = Wg16B + 262144;            // 48*16*64*8 = 393216
    half_t* wfrag  = Wih16B + 393216;           // 2*24*4*64*8 = 98304
    half_t* v16    = wfrag + 98304;             // 4096*256   = 1048576
    half_t* WT16B  = v16 + 1048576;             // 10*8*64*8  = 40960
    float* out  = (float*)d_out;

    // prep idx total: 1048576+768+262144+393216+98304+40960 = 1843968 = 7203*256
    prep_kernel<<<7203, 256, 0, stream>>>(v, Wvp1, Wvp2, Wg, wihf, wihb, bihf, bihb,
                                          whhf, whhb, bihC, v16, Wg16B, Wih16B,
                                          wfrag, WT16B);
    wv12_kernel<<<64, 256, 0, stream>>>(v16, WT16B, Wv1, Wv2);
    attn_kernel<<<1024, 256, 0, stream>>>(v, Wv1, Wv2, vw, g16);
    gatexp_kernel<<<128, 256, 0, stream>>>(g16, Wg16B, Wih16B, bihC, xpf, xpb);
    gru_kernel<<<2, 512, 0, stream>>>(xpf, xpb, wfrag, bhhf, bhhb, out);
}

// Round 7
// 729.786 us; speedup vs baseline: 1.0620x; 1.0620x over previous
//
#include <hip/hip_runtime.h>

// Problem constants
#define TP 512   // passage length
#define TB 8     // batch
#define TD 256   // input size
#define TH 75    // attn hidden
#define THP 80   // padded attn hidden (float4-friendly, pads zeroed)
#define TO 128   // GRU hidden

typedef _Float16 half_t;
typedef _Float16 half2v __attribute__((ext_vector_type(2)));
typedef _Float16 half4v __attribute__((ext_vector_type(4)));
typedef _Float16 half8v __attribute__((ext_vector_type(8)));
typedef float    float4v __attribute__((ext_vector_type(4)));

union H8 { half8v v8; half2v v2[4]; };

__device__ __forceinline__ float fast_rcp(float x) { return __builtin_amdgcn_rcpf(x); }
__device__ __forceinline__ float fast_tanh(float x) {
    return 1.0f - 2.0f * fast_rcp(1.0f + __expf(2.0f * x));
}
__device__ __forceinline__ float fast_sigmoid(float x) {
    return fast_rcp(1.0f + __expf(-x));
}
__device__ __forceinline__ float fdot2h(half2v a, half2v b, float c) {
#if __has_builtin(__builtin_amdgcn_fdot2)
    return __builtin_amdgcn_fdot2(a, b, c, false);
#else
    return c + (float)a[0] * (float)b[0] + (float)a[1] * (float)b[1];
#endif
}
// score partial: sum c * rcp(1+exp(2(a+b)));  tanh(x) = 1 - 2*rcp(1+exp(2x))
__device__ __forceinline__ float rterm4(float4 a, float4 b, float4 c) {
    float s;
    s  = c.x * fast_rcp(1.0f + __expf(2.0f * (a.x + b.x)));
    s += c.y * fast_rcp(1.0f + __expf(2.0f * (a.y + b.y)));
    s += c.z * fast_rcp(1.0f + __expf(2.0f * (a.z + b.z)));
    s += c.w * fast_rcp(1.0f + __expf(2.0f * (a.w + b.w)));
    return s;
}

// ---------------- prep: f16 casts, transposes, B-frag swizzles, whh16 -------
// B-frag layout (mfma_f32_16x16x32_f16): [nt][kt][lane][j] halfs with
// B[k = kt*32 + (lane>>4)*8 + j][n = nt*16 + (lane&15)]  (verified R5/R6).
__global__ __launch_bounds__(256) void prep_kernel(
    const float* __restrict__ v,
    const float* __restrict__ Wvp1, const float* __restrict__ Wvp2,
    const float* __restrict__ Wg,   const float* __restrict__ wihf,
    const float* __restrict__ wihb, const float* __restrict__ bihf,
    const float* __restrict__ bihb, const float* __restrict__ whhf,
    const float* __restrict__ whhb,
    float* __restrict__ bihC,
    half_t* __restrict__ v16, half_t* __restrict__ vT16,
    half_t* __restrict__ g16, half_t* __restrict__ Wg16B,
    half_t* __restrict__ Wih16B, half_t* __restrict__ whh16,
    half_t* __restrict__ WT16B)
{
    int idx = blockIdx.x * 256 + threadIdx.x;
    if (idx < 1048576) {                        // v cast + 3 layouts
        half_t val = (half_t)v[idx];
        v16[idx] = val;                          // [p*8+b][d]
        int row = idx >> 8, d = idx & 255;       // row = p*8+b
        g16[row * 512 + d] = val;                // g first half = v
        int p = idx >> 11, b = (idx >> 8) & 7;
        vT16[((b * 256 + d) << 9) + p] = val;    // [b][d][p]
        return;
    }
    idx -= 1048576;
    if (idx < 768) { bihC[idx] = (idx < 384) ? bihf[idx] : bihb[idx - 384]; return; }
    idx -= 768;
    if (idx < 262144) {                         // Wg16B (nt 0..31)
        int j = idx & 7, lane = (idx >> 3) & 63, kt = (idx >> 9) & 15, nt = idx >> 13;
        int o = nt * 16 + (lane & 15);
        int k = kt * 32 + ((lane >> 4) << 3) + j;
        Wg16B[idx] = (half_t)Wg[o * 512 + k];
        return;
    }
    idx -= 262144;
    if (idx < 393216) {                         // Wih16B (nt 0..47, o<384 fwd)
        int j = idx & 7, lane = (idx >> 3) & 63, kt = (idx >> 9) & 15, nt = idx >> 13;
        int o = nt * 16 + (lane & 15);
        int k = kt * 32 + ((lane >> 4) << 3) + j;
        Wih16B[idx] = (half_t)((o < 384) ? wihf[o * 512 + k] : wihb[(o - 384) * 512 + k]);
        return;
    }
    idx -= 393216;
    if (idx < 98304) {                          // whh16[dir][(g*128+o)*128+k]
        int d = idx / 49152, i = idx - d * 49152;
        whh16[idx] = (half_t)(d ? whhb[i] : whhf[i]);
        return;
    }
    idx -= 98304;
    if (idx < 40960) {                          // WT16B (nt 0..9): [Wvp1;Wvp2]
        int j = idx & 7, lane = (idx >> 3) & 63, kt = (idx >> 9) & 7, nt = idx >> 12;
        int o = nt * 16 + (lane & 15);
        int k = kt * 32 + ((lane >> 4) << 3) + j;
        float vv = 0.0f;
        if (o < 75)       vv = Wvp1[o * 256 + k];
        else if (o < 150) vv = Wvp2[(o - 75) * 256 + k];
        WT16B[idx] = (half_t)vv;
    }
}

// ---------------- Wv1/Wv2 via MFMA: [4096,160] = v16 @ WT16B ----------------
__global__ __launch_bounds__(256) void wv12_kernel(
    const half_t* __restrict__ v16, const half_t* __restrict__ WT16B,
    float* __restrict__ Wv1, float* __restrict__ Wv2)
{
    int tid = threadIdx.x;
    int lane = tid & 63, w = tid >> 6;
    int l15 = lane & 15, quad = lane >> 4;
    int r0 = blockIdx.x * 64 + w * 16;

    float4v acc[10];
#pragma unroll
    for (int nt = 0; nt < 10; ++nt) acc[nt] = (float4v){0.f, 0.f, 0.f, 0.f};

#pragma unroll
    for (int kt = 0; kt < 8; ++kt) {
        half8v a = *(const half8v*)(v16 + (r0 + l15) * 256 + kt * 32 + quad * 8);
#pragma unroll
        for (int nt = 0; nt < 10; ++nt) {
            half8v b = *(const half8v*)(WT16B + ((nt * 8 + kt) * 64 + lane) * 8);
            acc[nt] = __builtin_amdgcn_mfma_f32_16x16x32_f16(a, b, acc[nt], 0, 0, 0);
        }
    }
    // C/D: col = nt*16 + l15, row = r0 + quad*4 + r; rows are (p*8+b)
#pragma unroll
    for (int nt = 0; nt < 10; ++nt) {
        int col = nt * 16 + l15;
#pragma unroll
        for (int r = 0; r < 4; ++r) {
            int row = r0 + quad * 4 + r;
            int ob = ((row & 7) * TP + (row >> 3)) * THP;
            float val = acc[nt][r];
            if (col < 75)       Wv1[ob + col] = val;
            else if (col < 80)  { Wv2[ob + col - 75] = val; Wv1[ob + col] = 0.0f; }
            else if (col < 150) Wv2[ob + col - 75] = val;
            else if (col < 155) Wv2[ob + col - 75] = 0.0f;   // Wv2 pads
        }
    }
}

// -------- scores -> softmax(i) -> a16[b][j][i] (f16) ------------------------
// grid: b in [0,8) x 128 j-tiles of 4; block 256
__global__ __launch_bounds__(256) void score_kernel(
    const float* __restrict__ Wv1, const float* __restrict__ Wv2,
    const float* __restrict__ vw, half_t* __restrict__ a16)
{
    int tid = threadIdx.x;
    int b  = blockIdx.x >> 7;
    int j0 = (blockIdx.x & 127) * 4;
    __shared__ float wv1j[4 * THP];
    __shared__ float vws[THP];
    __shared__ float sc[4 * TP];

    if (tid < THP) vws[tid] = (tid < TH) ? vw[tid] : 0.0f;
    for (int e = tid; e < 4 * THP; e += 256) {
        int jj = e / THP, k = e - jj * THP;
        wv1j[e] = Wv1[(b * TP + j0 + jj) * THP + k];
    }
    __syncthreads();

    float Csum = 0.0f;
    {
        const float4* c4 = (const float4*)vws;
        for (int kk = 0; kk < 20; ++kk) { float4 c = c4[kk]; Csum += c.x + c.y + c.z + c.w; }
    }

    for (int rep = 0; rep < 2; ++rep) {
        int i = tid + rep * 256;
        const float4* row4 = (const float4*)(Wv2 + (b * TP + i) * THP);
        float acc[4] = {0.f, 0.f, 0.f, 0.f};
#pragma unroll
        for (int kt = 0; kt < 5; ++kt) {
            float4 r0 = row4[kt * 4 + 0], r1 = row4[kt * 4 + 1];
            float4 r2 = row4[kt * 4 + 2], r3 = row4[kt * 4 + 3];
            const float4* c4 = (const float4*)(vws + kt * 16);
            float4 c0 = c4[0], c1 = c4[1], c2 = c4[2], c3 = c4[3];
#pragma unroll
            for (int jj = 0; jj < 4; ++jj) {
                const float4* w1 = (const float4*)(wv1j + jj * THP + kt * 16);
                acc[jj] += rterm4(r0, w1[0], c0) + rterm4(r1, w1[1], c1)
                         + rterm4(r2, w1[2], c2) + rterm4(r3, w1[3], c3);
            }
        }
#pragma unroll
        for (int jj = 0; jj < 4; ++jj) sc[jj * TP + i] = Csum - 2.0f * acc[jj];
    }
    __syncthreads();

    // softmax over i, one wave per jj, then f16 store to a16[b][j][i]
    {
        int jj = tid >> 6, l = tid & 63;
        float m = -1e30f;
#pragma unroll
        for (int q = 0; q < 8; ++q) m = fmaxf(m, sc[jj * TP + l + q * 64]);
#pragma unroll
        for (int s = 32; s > 0; s >>= 1) m = fmaxf(m, __shfl_xor(m, s));
        float e[8];
        float sum = 0.0f;
#pragma unroll
        for (int q = 0; q < 8; ++q) { e[q] = __expf(sc[jj * TP + l + q * 64] - m); sum += e[q]; }
#pragma unroll
        for (int s = 32; s > 0; s >>= 1) sum += __shfl_xor(sum, s);
        float inv = fast_rcp(sum);
        half_t* arow = a16 + (b * TP + j0 + jj) * TP;
#pragma unroll
        for (int q = 0; q < 8; ++q) arow[l + q * 64] = (half_t)(e[q] * inv);
    }
}

// -------- context via MFMA: c[j,b,d] = sum_i a[b,j,i] * v[i,b,d] ------------
// grid 256 = b*32 + mt; 256 thr (4 waves). A-frags direct from a16 rows,
// B-frags direct from vT16[b][d][i]; no LDS. Writes g16 second half (f16).
__global__ __launch_bounds__(256) void context_kernel(
    const half_t* __restrict__ a16, const half_t* __restrict__ vT16,
    half_t* __restrict__ g16)
{
    int tid = threadIdx.x;
    int lane = tid & 63, w = tid >> 6;
    int l15 = lane & 15, quad = lane >> 4;
    int b  = blockIdx.x >> 5;
    int mt = blockIdx.x & 31;

    const half_t* arow = a16 + (b * TP + mt * 16 + l15) * TP;
    const half_t* vbase = vT16 + ((b * 256) << 9);

    float4v acc[4];
#pragma unroll
    for (int nti = 0; nti < 4; ++nti) acc[nti] = (float4v){0.f, 0.f, 0.f, 0.f};

#pragma unroll 4
    for (int kt = 0; kt < 16; ++kt) {
        half8v a = *(const half8v*)(arow + kt * 32 + quad * 8);
#pragma unroll
        for (int nti = 0; nti < 4; ++nti) {
            int d = (w * 4 + nti) * 16 + l15;
            half8v bb = *(const half8v*)(vbase + (d << 9) + kt * 32 + quad * 8);
            acc[nti] = __builtin_amdgcn_mfma_f32_16x16x32_f16(a, bb, acc[nti], 0, 0, 0);
        }
    }
    // C/D: col(d) = (w*4+nti)*16 + l15, row(j) = mt*16 + quad*4 + r
#pragma unroll
    for (int nti = 0; nti < 4; ++nti) {
        int d = (w * 4 + nti) * 16 + l15;
#pragma unroll
        for (int r = 0; r < 4; ++r) {
            int j = mt * 16 + quad * 4 + r;
            g16[(j * TB + b) * 512 + 256 + d] = (half_t)acc[nti][r];
        }
    }
}

// -------- MFMA gate (sigmoid(g Wg^T)*g) + GRU input projections -------------
__global__ __launch_bounds__(256, 1) void gatexp_kernel(
    const half_t* __restrict__ g16, const half_t* __restrict__ Wg16B,
    const half_t* __restrict__ Wih16B, const float* __restrict__ bihC,
    float* __restrict__ xpf, float* __restrict__ xpb)
{
    __shared__ half_t gA[32 * 520];      // rows padded to 520 halfs
    int tid = threadIdx.x;
    int r0 = blockIdx.x * 32;
    int lane = tid & 63, w = tid >> 6;
    int l15 = lane & 15, quad = lane >> 4;

    for (int e = tid; e < 2048; e += 256) {
        int row = e >> 6, c8 = e & 63;
        *(half8v*)(gA + row * 520 + c8 * 8) =
            *(const half8v*)(g16 + (r0 + row) * 512 + c8 * 8);
    }
    __syncthreads();

    float4v acc[2][8];
#pragma unroll
    for (int mi = 0; mi < 2; ++mi)
#pragma unroll
        for (int nti = 0; nti < 8; ++nti) acc[mi][nti] = (float4v){0.f, 0.f, 0.f, 0.f};

    for (int kt = 0; kt < 16; ++kt) {
        half8v a0 = *(const half8v*)(gA + l15 * 520 + kt * 32 + quad * 8);
        half8v a1 = *(const half8v*)(gA + (16 + l15) * 520 + kt * 32 + quad * 8);
#pragma unroll
        for (int nti = 0; nti < 8; ++nti) {
            half8v bb = *(const half8v*)(Wg16B + (((w * 8 + nti) * 16 + kt) * 64 + lane) * 8);
            acc[0][nti] = __builtin_amdgcn_mfma_f32_16x16x32_f16(a0, bb, acc[0][nti], 0, 0, 0);
            acc[1][nti] = __builtin_amdgcn_mfma_f32_16x16x32_f16(a1, bb, acc[1][nti], 0, 0, 0);
        }
    }
#pragma unroll
    for (int mi = 0; mi < 2; ++mi)
#pragma unroll
        for (int nti = 0; nti < 8; ++nti) {
            int colg = (w * 8 + nti) * 16 + l15;
#pragma unroll
            for (int r = 0; r < 4; ++r) {
                float gv = (float)gA[(mi * 16 + quad * 4 + r) * 520 + colg];
                acc[mi][nti][r] = fast_sigmoid(acc[mi][nti][r]) * gv;
            }
        }
    __syncthreads();
#pragma unroll
    for (int mi = 0; mi < 2; ++mi)
#pragma unroll
        for (int nti = 0; nti < 8; ++nti) {
            int colg = (w * 8 + nti) * 16 + l15;
#pragma unroll
            for (int r = 0; r < 4; ++r)
                gA[(mi * 16 + quad * 4 + r) * 520 + colg] = (half_t)acc[mi][nti][r];
        }
    __syncthreads();

    float4v c2[2][12];
#pragma unroll
    for (int mi = 0; mi < 2; ++mi)
#pragma unroll
        for (int nt2 = 0; nt2 < 12; ++nt2) {
            float bv = bihC[(w * 12 + nt2) * 16 + l15];
            c2[mi][nt2] = (float4v){bv, bv, bv, bv};
        }

    for (int kt = 0; kt < 16; ++kt) {
        half8v a0 = *(const half8v*)(gA + l15 * 520 + kt * 32 + quad * 8);
        half8v a1 = *(const half8v*)(gA + (16 + l15) * 520 + kt * 32 + quad * 8);
#pragma unroll
        for (int nt2 = 0; nt2 < 12; ++nt2) {
            half8v bb = *(const half8v*)(Wih16B + (((w * 12 + nt2) * 16 + kt) * 64 + lane) * 8);
            c2[0][nt2] = __builtin_amdgcn_mfma_f32_16x16x32_f16(a0, bb, c2[0][nt2], 0, 0, 0);
            c2[1][nt2] = __builtin_amdgcn_mfma_f32_16x16x32_f16(a1, bb, c2[1][nt2], 0, 0, 0);
        }
    }
#pragma unroll
    for (int mi = 0; mi < 2; ++mi)
#pragma unroll
        for (int nt2 = 0; nt2 < 12; ++nt2) {
            int col = (w * 12 + nt2) * 16 + l15;
            float* dst = (col < 384) ? (xpf + col) : (xpb + col - 384);
#pragma unroll
            for (int r = 0; r < 4; ++r)
                dst[(r0 + mi * 16 + quad * 4 + r) * 384] = c2[mi][nt2][r];
        }
}

// ---------------- GRU recurrence, dir-paired: one block per batch -----------
// 1024 threads = two independent 512-thread chains (dir = tid>>9), so each
// SIMD hosts waves of BOTH chains — one chain's latency phases overlap the
// other's issue phases. Within a chain: thread (o = t>>2, q = t&3), w_hh f16
// in VGPRs, h ping-pong f16 in LDS, fdot2, 1 barrier/step.
__global__ __launch_bounds__(1024) void gru_kernel(
    const float* __restrict__ xpf, const float* __restrict__ xpb,
    const half_t* __restrict__ whh16,
    const float* __restrict__ bhhf, const float* __restrict__ bhhb,
    float* __restrict__ out)
{
    int tid = threadIdx.x;
    int b   = blockIdx.x;
    int dir = tid >> 9;
    int t   = tid & 511;
    const float* xp  = dir ? xpb  : xpf;
    const float* bhh = dir ? bhhb : bhhf;
    const half_t* wbase = whh16 + dir * 3 * TO * TO;

    __shared__ __align__(16) half_t hb[2][2][TO];   // [dir][buf][o]

    int o = t >> 2, q = t & 3;

    H8 wr[4], wz[4], wn[4];
    {
        const half8v* pr = (const half8v*)(wbase + (o)          * TO + q * 32);
        const half8v* pz = (const half8v*)(wbase + (TO + o)     * TO + q * 32);
        const half8v* pn = (const half8v*)(wbase + (2 * TO + o) * TO + q * 32);
#pragma unroll
        for (int kk = 0; kk < 4; ++kk) { wr[kk].v8 = pr[kk]; wz[kk].v8 = pz[kk]; wn[kk].v8 = pn[kk]; }
    }

    float br = 0.f, bz = 0.f, bn = 0.f, h = 0.f;
    float xr = 0.f, xz = 0.f, xn = 0.f;
    if (q == 0) {
        br = bhh[o]; bz = bhh[TO + o]; bn = bhh[2 * TO + o];
        int t0 = dir ? (TP - 1) : 0;
        const float* xpt = xp + (t0 * TB + b) * 384;
        xr = xpt[o]; xz = xpt[TO + o]; xn = xpt[2 * TO + o];
    }
    if (t < TO) hb[dir][0][t] = (half_t)0.0f;
    __syncthreads();

    for (int s = 0; s < TP; ++s) {
        int ts = dir ? (TP - 1 - s) : s;
        int cur = s & 1;
        const half8v* h8 = (const half8v*)(&hb[dir][cur][q * 32]);
        H8 hv[4];
#pragma unroll
        for (int kk = 0; kk < 4; ++kk) hv[kk].v8 = h8[kk];

        float ar = 0.f, az = 0.f, an = 0.f;
#pragma unroll
        for (int kk = 0; kk < 4; ++kk) {
#pragma unroll
            for (int j = 0; j < 4; ++j) {
                half2v hp = hv[kk].v2[j];
                ar = fdot2h(wr[kk].v2[j], hp, ar);
                az = fdot2h(wz[kk].v2[j], hp, az);
                an = fdot2h(wn[kk].v2[j], hp, an);
            }
        }
        ar += __shfl_xor(ar, 1); ar += __shfl_xor(ar, 2);
        az += __shfl_xor(az, 1); az += __shfl_xor(az, 2);
        an += __shfl_xor(an, 1); an += __shfl_xor(an, 2);
        if (q == 0) {
            float r = fast_sigmoid(xr + ar + br);
            float z = fast_sigmoid(xz + az + bz);
            float n = fast_tanh(xn + r * (an + bn));
            h = (1.0f - z) * n + z * h;
            hb[dir][cur ^ 1][o] = (half_t)h;
            out[(ts * TB + b) * 256 + dir * TO + o] = h;
            int sn = (s + 1 < TP) ? s + 1 : s;
            int tn = dir ? (TP - 1 - sn) : sn;
            const float* xpt = xp + (tn * TB + b) * 384;
            xr = xpt[o]; xz = xpt[TO + o]; xn = xpt[2 * TO + o];
        }
        __syncthreads();
    }
}

extern "C" void kernel_launch(void* const* d_in, const int* in_sizes, int n_in,
                              void* d_out, int out_size, void* d_ws, size_t ws_size,
                              hipStream_t stream) {
    const float* v    = (const float*)d_in[0];
    const float* Wvp1 = (const float*)d_in[1];
    const float* Wvp2 = (const float*)d_in[2];
    const float* vw   = (const float*)d_in[3];
    const float* Wg   = (const float*)d_in[4];
    const float* wihf = (const float*)d_in[5];
    const float* whhf = (const float*)d_in[6];
    const float* bihf = (const float*)d_in[7];
    const float* bhhf = (const float*)d_in[8];
    const float* wihb = (const float*)d_in[9];
    const float* whhb = (const float*)d_in[10];
    const float* bihb = (const float*)d_in[11];
    const float* bhhb = (const float*)d_in[12];

    float* ws   = (float*)d_ws;
    float* bihC = ws;                    // 768 f32
    float* Wv1  = bihC + 768;            // 8*512*80 = 327680
    float* Wv2  = Wv1 + 327680;          // 327680
    float* xpf  = Wv2 + 327680;          // 4096*384 = 1572864
    float* xpb  = xpf + 1572864;         // 1572864
    half_t* g16    = (half_t*)(xpb + 1572864);  // 4096*512   = 2097152 halfs
    half_t* Wg16B  = g16 + 2097152;             // 262144
    half_t* Wih16B = Wg16B + 262144;            // 393216
    half_t* whh16  = Wih16B + 393216;           // 98304
    half_t* v16    = whh16 + 98304;             // 1048576
    half_t* WT16B  = v16 + 1048576;             // 40960
    half_t* vT16   = WT16B + 40960;             // 8*256*512  = 1048576
    half_t* a16    = vT16 + 1048576;            // 8*512*512  = 2097152
    float* out  = (float*)d_out;

    // prep idx total: 1048576+768+262144+393216+98304+40960 = 1843968 = 7203*256
    prep_kernel<<<7203, 256, 0, stream>>>(v, Wvp1, Wvp2, Wg, wihf, wihb, bihf, bihb,
                                          whhf, whhb, bihC, v16, vT16, g16,
                                          Wg16B, Wih16B, whh16, WT16B);
    wv12_kernel<<<64, 256, 0, stream>>>(v16, WT16B, Wv1, Wv2);
    score_kernel<<<1024, 256, 0, stream>>>(Wv1, Wv2, vw, a16);
    context_kernel<<<256, 256, 0, stream>>>(a16, vT16, g16);
    gatexp_kernel<<<128, 256, 0, stream>>>(g16, Wg16B, Wih16B, bihC, xpf, xpb);
    gru_kernel<<<8, 1024, 0, stream>>>(xpf, xpb, whh16, bhhf, bhhb, out);
}

// Round 8
// 514.531 us; speedup vs baseline: 1.5063x; 1.4184x over previous
//
#include <hip/hip_runtime.h>

// Problem constants
#define TP 512   // passage length
#define TB 8     // batch
#define TD 256   // input size
#define TH 75    // attn hidden
#define THP 80   // padded attn hidden (float4-friendly, pads zeroed)
#define TO 128   // GRU hidden

typedef _Float16 half_t;
typedef _Float16 half2v __attribute__((ext_vector_type(2)));
typedef _Float16 half4v __attribute__((ext_vector_type(4)));
typedef _Float16 half8v __attribute__((ext_vector_type(8)));
typedef float    float4v __attribute__((ext_vector_type(4)));

union H8 { half8v v8; half2v v2[4]; };

__device__ __forceinline__ float fast_rcp(float x) { return __builtin_amdgcn_rcpf(x); }
__device__ __forceinline__ float fast_tanh(float x) {
    return 1.0f - 2.0f * fast_rcp(1.0f + __expf(2.0f * x));
}
__device__ __forceinline__ float fast_sigmoid(float x) {
    return fast_rcp(1.0f + __expf(-x));
}
__device__ __forceinline__ float fdot2h(half2v a, half2v b, float c) {
#if __has_builtin(__builtin_amdgcn_fdot2)
    return __builtin_amdgcn_fdot2(a, b, c, false);
#else
    return c + (float)a[0] * (float)b[0] + (float)a[1] * (float)b[1];
#endif
}

// ---------------- prep: f16 casts, transposes, B-frag swizzles, whh16 -------
// B-frag layout (mfma_f32_16x16x32_f16): [nt][kt][lane][j] halfs with
// B[k = kt*32 + (lane>>4)*8 + j][n = nt*16 + (lane&15)]  (verified R5/R6).
__global__ __launch_bounds__(256) void prep_kernel(
    const float* __restrict__ v,
    const float* __restrict__ Wvp1, const float* __restrict__ Wvp2,
    const float* __restrict__ Wg,   const float* __restrict__ wihf,
    const float* __restrict__ wihb, const float* __restrict__ bihf,
    const float* __restrict__ bihb, const float* __restrict__ whhf,
    const float* __restrict__ whhb,
    float* __restrict__ bihC,
    half_t* __restrict__ v16, half_t* __restrict__ vT16,
    half_t* __restrict__ g16, half_t* __restrict__ Wg16B,
    half_t* __restrict__ Wih16B, half_t* __restrict__ whh16,
    half_t* __restrict__ WT16B)
{
    int idx = blockIdx.x * 256 + threadIdx.x;
    if (idx < 1048576) {                        // v cast + 3 layouts
        half_t val = (half_t)v[idx];
        v16[idx] = val;                          // [p*8+b][d]
        int row = idx >> 8, d = idx & 255;       // row = p*8+b
        g16[row * 512 + d] = val;                // g first half = v
        int p = idx >> 11, b = (idx >> 8) & 7;
        vT16[((b * 256 + d) << 9) + p] = val;    // [b][d][p]
        return;
    }
    idx -= 1048576;
    if (idx < 768) { bihC[idx] = (idx < 384) ? bihf[idx] : bihb[idx - 384]; return; }
    idx -= 768;
    if (idx < 262144) {                         // Wg16B (nt 0..31)
        int j = idx & 7, lane = (idx >> 3) & 63, kt = (idx >> 9) & 15, nt = idx >> 13;
        int o = nt * 16 + (lane & 15);
        int k = kt * 32 + ((lane >> 4) << 3) + j;
        Wg16B[idx] = (half_t)Wg[o * 512 + k];
        return;
    }
    idx -= 262144;
    if (idx < 393216) {                         // Wih16B (nt 0..47, o<384 fwd)
        int j = idx & 7, lane = (idx >> 3) & 63, kt = (idx >> 9) & 15, nt = idx >> 13;
        int o = nt * 16 + (lane & 15);
        int k = kt * 32 + ((lane >> 4) << 3) + j;
        Wih16B[idx] = (half_t)((o < 384) ? wihf[o * 512 + k] : wihb[(o - 384) * 512 + k]);
        return;
    }
    idx -= 393216;
    if (idx < 98304) {                          // whh16[dir][(g*128+o)*128+k]
        int d = idx / 49152, i = idx - d * 49152;
        whh16[idx] = (half_t)(d ? whhb[i] : whhf[i]);
        return;
    }
    idx -= 98304;
    if (idx < 40960) {                          // WT16B (nt 0..9): [Wvp1;Wvp2]
        int j = idx & 7, lane = (idx >> 3) & 63, kt = (idx >> 9) & 7, nt = idx >> 12;
        int o = nt * 16 + (lane & 15);
        int k = kt * 32 + ((lane >> 4) << 3) + j;
        float vv = 0.0f;
        if (o < 75)       vv = Wvp1[o * 256 + k];
        else if (o < 150) vv = Wvp2[(o - 75) * 256 + k];
        WT16B[idx] = (half_t)vv;
    }
}

// ---------------- Wv1/Wv2T via MFMA: [4096,160] = v16 @ WT16B ---------------
// Outputs PRE-DOUBLED (fold the 2x of tanh's exp(2x) into the weights).
// Wv1 row-major [b][p][80] (pads 0); Wv2T transposed [b][h(80)][p] for
// coalesced lane-consecutive-i reads in score_kernel.
__global__ __launch_bounds__(256) void wv12_kernel(
    const half_t* __restrict__ v16, const half_t* __restrict__ WT16B,
    float* __restrict__ Wv1, float* __restrict__ Wv2T)
{
    int tid = threadIdx.x;
    int lane = tid & 63, w = tid >> 6;
    int l15 = lane & 15, quad = lane >> 4;
    int r0 = blockIdx.x * 64 + w * 16;

    float4v acc[10];
#pragma unroll
    for (int nt = 0; nt < 10; ++nt) acc[nt] = (float4v){0.f, 0.f, 0.f, 0.f};

#pragma unroll
    for (int kt = 0; kt < 8; ++kt) {
        half8v a = *(const half8v*)(v16 + (r0 + l15) * 256 + kt * 32 + quad * 8);
#pragma unroll
        for (int nt = 0; nt < 10; ++nt) {
            half8v b = *(const half8v*)(WT16B + ((nt * 8 + kt) * 64 + lane) * 8);
            acc[nt] = __builtin_amdgcn_mfma_f32_16x16x32_f16(a, b, acc[nt], 0, 0, 0);
        }
    }
    // C/D: col = nt*16 + l15, row = r0 + quad*4 + r; rows are (p*8+b)
#pragma unroll
    for (int nt = 0; nt < 10; ++nt) {
        int col = nt * 16 + l15;
#pragma unroll
        for (int r = 0; r < 4; ++r) {
            int row = r0 + quad * 4 + r;
            int p = row >> 3, b = row & 7;
            int ob = (b * TP + p) * THP;
            float val2 = 2.0f * acc[nt][r];
            if (col < 75)       Wv1[ob + col] = val2;
            else if (col < 80)  { Wv1[ob + col] = 0.0f;
                                  Wv2T[(b * THP + col - 75) * TP + p] = val2; }
            else if (col < 150) Wv2T[(b * THP + col - 75) * TP + p] = val2;
            else if (col < 155) Wv2T[(b * THP + col - 75) * TP + p] = 0.0f;
        }
    }
}

// -------- scores -> softmax(i) -> a16[b][j][i] (f16) ------------------------
// grid: b in [0,8) x 128 j-tiles of 4; block 256. Wv2T reads are coalesced
// (lane-consecutive i); Wv1/Wv2T pre-doubled so exp arg is just (a+b).
__global__ __launch_bounds__(256) void score_kernel(
    const float* __restrict__ Wv1, const float* __restrict__ Wv2T,
    const float* __restrict__ vw, half_t* __restrict__ a16)
{
    int tid = threadIdx.x;
    int b  = blockIdx.x >> 7;
    int j0 = (blockIdx.x & 127) * 4;
    __shared__ float wv1j[4 * THP];
    __shared__ float vws[THP];
    __shared__ float sc[4 * TP];

    if (tid < THP) vws[tid] = (tid < TH) ? vw[tid] : 0.0f;
    for (int e = tid; e < 4 * THP; e += 256) {
        int jj = e / THP, k = e - jj * THP;
        wv1j[e] = Wv1[(b * TP + j0 + jj) * THP + k];
    }
    __syncthreads();

    float Csum = 0.0f;
    {
        const float4* c4 = (const float4*)vws;
        for (int kk = 0; kk < 20; ++kk) { float4 c = c4[kk]; Csum += c.x + c.y + c.z + c.w; }
    }

    int i0 = tid, i1 = tid + 256;
    float acc0[4] = {0.f,0.f,0.f,0.f}, acc1[4] = {0.f,0.f,0.f,0.f};
    const float* wvt = Wv2T + b * THP * TP;
#pragma unroll
    for (int kt = 0; kt < 5; ++kt) {
        float r0v[16], r1v[16];
#pragma unroll
        for (int u = 0; u < 16; ++u) {
            const float* colp = wvt + (kt * 16 + u) * TP;
            r0v[u] = colp[i0];
            r1v[u] = colp[i1];
        }
        const float* cp = vws + kt * 16;
#pragma unroll
        for (int jj = 0; jj < 4; ++jj) {
            const float* w1 = wv1j + jj * THP + kt * 16;
            float s0 = 0.f, s1 = 0.f;
#pragma unroll
            for (int u = 0; u < 16; ++u) {
                float cu = cp[u], wu = w1[u];
                s0 += cu * fast_rcp(1.0f + __expf(r0v[u] + wu));
                s1 += cu * fast_rcp(1.0f + __expf(r1v[u] + wu));
            }
            acc0[jj] += s0; acc1[jj] += s1;
        }
    }
#pragma unroll
    for (int jj = 0; jj < 4; ++jj) {
        sc[jj * TP + i0] = Csum - 2.0f * acc0[jj];
        sc[jj * TP + i1] = Csum - 2.0f * acc1[jj];
    }
    __syncthreads();

    // softmax over i, one wave per jj, then f16 store to a16[b][j][i]
    {
        int jj = tid >> 6, l = tid & 63;
        float m = -1e30f;
#pragma unroll
        for (int q = 0; q < 8; ++q) m = fmaxf(m, sc[jj * TP + l + q * 64]);
#pragma unroll
        for (int s = 32; s > 0; s >>= 1) m = fmaxf(m, __shfl_xor(m, s));
        float e[8];
        float sum = 0.0f;
#pragma unroll
        for (int q = 0; q < 8; ++q) { e[q] = __expf(sc[jj * TP + l + q * 64] - m); sum += e[q]; }
#pragma unroll
        for (int s = 32; s > 0; s >>= 1) sum += __shfl_xor(sum, s);
        float inv = fast_rcp(sum);
        half_t* arow = a16 + (b * TP + j0 + jj) * TP;
#pragma unroll
        for (int q = 0; q < 8; ++q) arow[l + q * 64] = (half_t)(e[q] * inv);
    }
}

// -------- context via MFMA: c[j,b,d] = sum_i a[b,j,i] * v[i,b,d] ------------
__global__ __launch_bounds__(256) void context_kernel(
    const half_t* __restrict__ a16, const half_t* __restrict__ vT16,
    half_t* __restrict__ g16)
{
    int tid = threadIdx.x;
    int lane = tid & 63, w = tid >> 6;
    int l15 = lane & 15, quad = lane >> 4;
    int b  = blockIdx.x >> 5;
    int mt = blockIdx.x & 31;

    const half_t* arow = a16 + (b * TP + mt * 16 + l15) * TP;
    const half_t* vbase = vT16 + ((b * 256) << 9);

    float4v acc[4];
#pragma unroll
    for (int nti = 0; nti < 4; ++nti) acc[nti] = (float4v){0.f, 0.f, 0.f, 0.f};

#pragma unroll 4
    for (int kt = 0; kt < 16; ++kt) {
        half8v a = *(const half8v*)(arow + kt * 32 + quad * 8);
#pragma unroll
        for (int nti = 0; nti < 4; ++nti) {
            int d = (w * 4 + nti) * 16 + l15;
            half8v bb = *(const half8v*)(vbase + (d << 9) + kt * 32 + quad * 8);
            acc[nti] = __builtin_amdgcn_mfma_f32_16x16x32_f16(a, bb, acc[nti], 0, 0, 0);
        }
    }
#pragma unroll
    for (int nti = 0; nti < 4; ++nti) {
        int d = (w * 4 + nti) * 16 + l15;
#pragma unroll
        for (int r = 0; r < 4; ++r) {
            int j = mt * 16 + quad * 4 + r;
            g16[(j * TB + b) * 512 + 256 + d] = (half_t)acc[nti][r];
        }
    }
}

// -------- MFMA gate (sigmoid(g Wg^T)*g) + GRU input projections -------------
__global__ __launch_bounds__(256, 1) void gatexp_kernel(
    const half_t* __restrict__ g16, const half_t* __restrict__ Wg16B,
    const half_t* __restrict__ Wih16B, const float* __restrict__ bihC,
    float* __restrict__ xpf, float* __restrict__ xpb)
{
    __shared__ half_t gA[32 * 520];      // rows padded to 520 halfs
    int tid = threadIdx.x;
    int r0 = blockIdx.x * 32;
    int lane = tid & 63, w = tid >> 6;
    int l15 = lane & 15, quad = lane >> 4;

    for (int e = tid; e < 2048; e += 256) {
        int row = e >> 6, c8 = e & 63;
        *(half8v*)(gA + row * 520 + c8 * 8) =
            *(const half8v*)(g16 + (r0 + row) * 512 + c8 * 8);
    }
    __syncthreads();

    float4v acc[2][8];
#pragma unroll
    for (int mi = 0; mi < 2; ++mi)
#pragma unroll
        for (int nti = 0; nti < 8; ++nti) acc[mi][nti] = (float4v){0.f, 0.f, 0.f, 0.f};

    for (int kt = 0; kt < 16; ++kt) {
        half8v a0 = *(const half8v*)(gA + l15 * 520 + kt * 32 + quad * 8);
        half8v a1 = *(const half8v*)(gA + (16 + l15) * 520 + kt * 32 + quad * 8);
#pragma unroll
        for (int nti = 0; nti < 8; ++nti) {
            half8v bb = *(const half8v*)(Wg16B + (((w * 8 + nti) * 16 + kt) * 64 + lane) * 8);
            acc[0][nti] = __builtin_amdgcn_mfma_f32_16x16x32_f16(a0, bb, acc[0][nti], 0, 0, 0);
            acc[1][nti] = __builtin_amdgcn_mfma_f32_16x16x32_f16(a1, bb, acc[1][nti], 0, 0, 0);
        }
    }
#pragma unroll
    for (int mi = 0; mi < 2; ++mi)
#pragma unroll
        for (int nti = 0; nti < 8; ++nti) {
            int colg = (w * 8 + nti) * 16 + l15;
#pragma unroll
            for (int r = 0; r < 4; ++r) {
                float gv = (float)gA[(mi * 16 + quad * 4 + r) * 520 + colg];
                acc[mi][nti][r] = fast_sigmoid(acc[mi][nti][r]) * gv;
            }
        }
    __syncthreads();
#pragma unroll
    for (int mi = 0; mi < 2; ++mi)
#pragma unroll
        for (int nti = 0; nti < 8; ++nti) {
            int colg = (w * 8 + nti) * 16 + l15;
#pragma unroll
            for (int r = 0; r < 4; ++r)
                gA[(mi * 16 + quad * 4 + r) * 520 + colg] = (half_t)acc[mi][nti][r];
        }
    __syncthreads();

    float4v c2[2][12];
#pragma unroll
    for (int mi = 0; mi < 2; ++mi)
#pragma unroll
        for (int nt2 = 0; nt2 < 12; ++nt2) {
            float bv = bihC[(w * 12 + nt2) * 16 + l15];
            c2[mi][nt2] = (float4v){bv, bv, bv, bv};
        }

    for (int kt = 0; kt < 16; ++kt) {
        half8v a0 = *(const half8v*)(gA + l15 * 520 + kt * 32 + quad * 8);
        half8v a1 = *(const half8v*)(gA + (16 + l15) * 520 + kt * 32 + quad * 8);
#pragma unroll
        for (int nt2 = 0; nt2 < 12; ++nt2) {
            half8v bb = *(const half8v*)(Wih16B + (((w * 12 + nt2) * 16 + kt) * 64 + lane) * 8);
            c2[0][nt2] = __builtin_amdgcn_mfma_f32_16x16x32_f16(a0, bb, c2[0][nt2], 0, 0, 0);
            c2[1][nt2] = __builtin_amdgcn_mfma_f32_16x16x32_f16(a1, bb, c2[1][nt2], 0, 0, 0);
        }
    }
#pragma unroll
    for (int mi = 0; mi < 2; ++mi)
#pragma unroll
        for (int nt2 = 0; nt2 < 12; ++nt2) {
            int col = (w * 12 + nt2) * 16 + l15;
            float* dst = (col < 384) ? (xpf + col) : (xpb + col - 384);
#pragma unroll
            for (int r = 0; r < 4; ++r)
                dst[(r0 + mi * 16 + quad * 4 + r) * 384] = c2[mi][nt2][r];
        }
}

// ---------------- GRU recurrence, one block per (dir, batch) ----------------
// R5 structure: 512 threads, (o = tid>>2, q = tid&3), w_hh f16 in VGPRs,
// h ping-pong f16 in LDS, fdot2. KEY FIX vs R5: raw `s_waitcnt lgkmcnt(0);
// s_barrier` instead of __syncthreads() — does NOT drain vmcnt, so the xp
// prefetch loads and out-stores stay in flight across the step boundary
// (their latency is hidden by the next step's matvec instead of exposed
// in the serial barrier chain).
__global__ __launch_bounds__(512) void gru_kernel(
    const float* __restrict__ xpf, const float* __restrict__ xpb,
    const half_t* __restrict__ whh16,
    const float* __restrict__ bhhf, const float* __restrict__ bhhb,
    float* __restrict__ out)
{
    int tid = threadIdx.x;
    int dir = blockIdx.x >> 3;
    int b   = blockIdx.x & 7;
    const float* xp  = dir ? xpb  : xpf;
    const float* bhh = dir ? bhhb : bhhf;
    const half_t* wbase = whh16 + dir * 3 * TO * TO;

    __shared__ __align__(16) half_t hb[2][TO];

    int o = tid >> 2, q = tid & 3;

    H8 wr[4], wz[4], wn[4];
    {
        const half8v* pr = (const half8v*)(wbase + (o)          * TO + q * 32);
        const half8v* pz = (const half8v*)(wbase + (TO + o)     * TO + q * 32);
        const half8v* pn = (const half8v*)(wbase + (2 * TO + o) * TO + q * 32);
#pragma unroll
        for (int kk = 0; kk < 4; ++kk) { wr[kk].v8 = pr[kk]; wz[kk].v8 = pz[kk]; wn[kk].v8 = pn[kk]; }
    }

    float br = 0.f, bz = 0.f, bn = 0.f, h = 0.f;
    float xr = 0.f, xz = 0.f, xn = 0.f;
    if (q == 0) {
        br = bhh[o]; bz = bhh[TO + o]; bn = bhh[2 * TO + o];
        int t0 = dir ? (TP - 1) : 0;
        const float* xpt = xp + (t0 * TB + b) * 384;
        xr = xpt[o]; xz = xpt[TO + o]; xn = xpt[2 * TO + o];
    }
    if (tid < TO) hb[0][tid] = (half_t)0.0f;
    __syncthreads();

    for (int s = 0; s < TP; ++s) {
        int t = dir ? (TP - 1 - s) : s;
        int cur = s & 1;
        const half8v* h8 = (const half8v*)(&hb[cur][q * 32]);
        H8 hv[4];
#pragma unroll
        for (int kk = 0; kk < 4; ++kk) hv[kk].v8 = h8[kk];

        float ar = 0.f, az = 0.f, an = 0.f;
#pragma unroll
        for (int kk = 0; kk < 4; ++kk) {
#pragma unroll
            for (int j = 0; j < 4; ++j) {
                half2v hp = hv[kk].v2[j];
                ar = fdot2h(wr[kk].v2[j], hp, ar);
                az = fdot2h(wz[kk].v2[j], hp, az);
                an = fdot2h(wn[kk].v2[j], hp, an);
            }
        }
        ar += __shfl_xor(ar, 1); ar += __shfl_xor(ar, 2);
        az += __shfl_xor(az, 1); az += __shfl_xor(az, 2);
        an += __shfl_xor(an, 1); an += __shfl_xor(an, 2);
        if (q == 0) {
            float r = fast_sigmoid(xr + ar + br);
            float z = fast_sigmoid(xz + az + bz);
            float n = fast_tanh(xn + r * (an + bn));
            h = (1.0f - z) * n + z * h;
            hb[cur ^ 1][o] = (half_t)h;
            out[(t * TB + b) * 256 + dir * TO + o] = h;
            int sn = (s + 1 < TP) ? s + 1 : s;
            int tn = dir ? (TP - 1 - sn) : sn;
            const float* xpt = xp + (tn * TB + b) * 384;
            xr = xpt[o]; xz = xpt[TO + o]; xn = xpt[2 * TO + o];
        }
        // LDS-only barrier: do NOT drain vmcnt (xp prefetch / out stores)
        asm volatile("s_waitcnt lgkmcnt(0)\n\ts_barrier" ::: "memory");
    }
}

extern "C" void kernel_launch(void* const* d_in, const int* in_sizes, int n_in,
                              void* d_out, int out_size, void* d_ws, size_t ws_size,
                              hipStream_t stream) {
    const float* v    = (const float*)d_in[0];
    const float* Wvp1 = (const float*)d_in[1];
    const float* Wvp2 = (const float*)d_in[2];
    const float* vw   = (const float*)d_in[3];
    const float* Wg   = (const float*)d_in[4];
    const float* wihf = (const float*)d_in[5];
    const float* whhf = (const float*)d_in[6];
    const float* bihf = (const float*)d_in[7];
    const float* bhhf = (const float*)d_in[8];
    const float* wihb = (const float*)d_in[9];
    const float* whhb = (const float*)d_in[10];
    const float* bihb = (const float*)d_in[11];
    const float* bhhb = (const float*)d_in[12];

    float* ws   = (float*)d_ws;
    float* bihC = ws;                    // 768 f32
    float* Wv1  = bihC + 768;            // 8*512*80 = 327680
    float* Wv2T = Wv1 + 327680;          // 8*80*512 = 327680 (transposed)
    float* xpf  = Wv2T + 327680;         // 4096*384 = 1572864
    float* xpb  = xpf + 1572864;         // 1572864
    half_t* g16    = (half_t*)(xpb + 1572864);  // 4096*512   = 2097152 halfs
    half_t* Wg16B  = g16 + 2097152;             // 262144
    half_t* Wih16B = Wg16B + 262144;            // 393216
    half_t* whh16  = Wih16B + 393216;           // 98304
    half_t* v16    = whh16 + 98304;             // 1048576
    half_t* WT16B  = v16 + 1048576;             // 40960
    half_t* vT16   = WT16B + 40960;             // 8*256*512  = 1048576
    half_t* a16    = vT16 + 1048576;            // 8*512*512  = 2097152
    float* out  = (float*)d_out;

    // prep idx total: 1048576+768+262144+393216+98304+40960 = 1843968 = 7203*256
    prep_kernel<<<7203, 256, 0, stream>>>(v, Wvp1, Wvp2, Wg, wihf, wihb, bihf, bihb,
                                          whhf, whhb, bihC, v16, vT16, g16,
                                          Wg16B, Wih16B, whh16, WT16B);
    wv12_kernel<<<64, 256, 0, stream>>>(v16, WT16B, Wv1, Wv2T);
    score_kernel<<<1024, 256, 0, stream>>>(Wv1, Wv2T, vw, a16);
    context_kernel<<<256, 256, 0, stream>>>(a16, vT16, g16);
    gatexp_kernel<<<128, 256, 0, stream>>>(g16, Wg16B, Wih16B, bihC, xpf, xpb);
    gru_kernel<<<16, 512, 0, stream>>>(xpf, xpb, whh16, bhhf, bhhb, out);
}

// Round 9
// 478.737 us; speedup vs baseline: 1.6189x; 1.0748x over previous
//
#include <hip/hip_runtime.h>

// Problem constants
#define TP 512   // passage length
#define TB 8     // batch
#define TD 256   // input size
#define TH 75    // attn hidden
#define THP 80   // padded attn hidden (float4-friendly, pads zeroed)
#define TO 128   // GRU hidden

typedef _Float16 half_t;
typedef _Float16 half2v __attribute__((ext_vector_type(2)));
typedef _Float16 half4v __attribute__((ext_vector_type(4)));
typedef _Float16 half8v __attribute__((ext_vector_type(8)));
typedef float    float4v __attribute__((ext_vector_type(4)));

union H8 { half8v v8; half2v v2[4]; };

__device__ __forceinline__ float fast_rcp(float x) { return __builtin_amdgcn_rcpf(x); }
__device__ __forceinline__ float fast_tanh(float x) {
    return 1.0f - 2.0f * fast_rcp(1.0f + __expf(2.0f * x));
}
__device__ __forceinline__ float fast_sigmoid(float x) {
    return fast_rcp(1.0f + __expf(-x));
}
__device__ __forceinline__ float fdot2h(half2v a, half2v b, float c) {
#if __has_builtin(__builtin_amdgcn_fdot2)
    return __builtin_amdgcn_fdot2(a, b, c, false);
#else
    return c + (float)a[0] * (float)b[0] + (float)a[1] * (float)b[1];
#endif
}
// quad butterfly sum via DPP (VALU pipe, not DS): after this all 4 lanes of
// each quad hold the 4-lane sum. quad_perm [1,0,3,2]=0xB1, [2,3,0,1]=0x4E.
__device__ __forceinline__ float quad_sum_dpp(float v) {
    int i1 = __builtin_amdgcn_update_dpp(0, __builtin_bit_cast(int, v), 0xB1, 0xF, 0xF, true);
    v = v + __builtin_bit_cast(float, i1);
    int i2 = __builtin_amdgcn_update_dpp(0, __builtin_bit_cast(int, v), 0x4E, 0xF, 0xF, true);
    return v + __builtin_bit_cast(float, i2);
}

// ---------------- prep: f16 casts, B-frag swizzles, whh16 -------------------
// B-frag layout (mfma_f32_16x16x32_f16): [nt][kt][lane][j] halfs with
// B[k = kt*32 + (lane>>4)*8 + j][n = nt*16 + (lane&15)]  (verified R5/R6).
__global__ __launch_bounds__(256) void prep_kernel(
    const float* __restrict__ v,
    const float* __restrict__ Wvp1, const float* __restrict__ Wvp2,
    const float* __restrict__ Wg,   const float* __restrict__ wihf,
    const float* __restrict__ wihb, const float* __restrict__ bihf,
    const float* __restrict__ bihb, const float* __restrict__ whhf,
    const float* __restrict__ whhb,
    float* __restrict__ bihC,
    half_t* __restrict__ v16, half_t* __restrict__ g16,
    half_t* __restrict__ Wg16B, half_t* __restrict__ Wih16B,
    half_t* __restrict__ whh16, half_t* __restrict__ WT16B)
{
    int idx = blockIdx.x * 256 + threadIdx.x;
    if (idx < 1048576) {                        // v cast (coalesced)
        half_t val = (half_t)v[idx];
        v16[idx] = val;                          // [p*8+b][d]
        int row = idx >> 8, d = idx & 255;       // row = p*8+b
        g16[row * 512 + d] = val;                // g first half = v
        return;
    }
    idx -= 1048576;
    if (idx < 768) { bihC[idx] = (idx < 384) ? bihf[idx] : bihb[idx - 384]; return; }
    idx -= 768;
    if (idx < 262144) {                         // Wg16B (nt 0..31)
        int j = idx & 7, lane = (idx >> 3) & 63, kt = (idx >> 9) & 15, nt = idx >> 13;
        int o = nt * 16 + (lane & 15);
        int k = kt * 32 + ((lane >> 4) << 3) + j;
        Wg16B[idx] = (half_t)Wg[o * 512 + k];
        return;
    }
    idx -= 262144;
    if (idx < 393216) {                         // Wih16B (nt 0..47, o<384 fwd)
        int j = idx & 7, lane = (idx >> 3) & 63, kt = (idx >> 9) & 15, nt = idx >> 13;
        int o = nt * 16 + (lane & 15);
        int k = kt * 32 + ((lane >> 4) << 3) + j;
        Wih16B[idx] = (half_t)((o < 384) ? wihf[o * 512 + k] : wihb[(o - 384) * 512 + k]);
        return;
    }
    idx -= 393216;
    if (idx < 98304) {                          // whh16[dir][(g*128+o)*128+k]
        int d = idx / 49152, i = idx - d * 49152;
        whh16[idx] = (half_t)(d ? whhb[i] : whhf[i]);
        return;
    }
    idx -= 98304;
    if (idx < 40960) {                          // WT16B (nt 0..9): [Wvp1;Wvp2]
        int j = idx & 7, lane = (idx >> 3) & 63, kt = (idx >> 9) & 7, nt = idx >> 12;
        int o = nt * 16 + (lane & 15);
        int k = kt * 32 + ((lane >> 4) << 3) + j;
        float vv = 0.0f;
        if (o < 75)       vv = Wvp1[o * 256 + k];
        else if (o < 150) vv = Wvp2[(o - 75) * 256 + k];
        WT16B[idx] = (half_t)vv;
    }
}

// ---------------- vT16[b][d][p] tiled transpose (coalesced R/W) -------------
// grid 256 = b(8) x pt(8) x dt(4); 64x64 f32->f16 tile through LDS.
__global__ __launch_bounds__(256) void vtrans_kernel(
    const float* __restrict__ v, half_t* __restrict__ vT16)
{
    __shared__ half_t lt[64 * 66];   // [d_local][p_local], stride 66
    int t = threadIdx.x;
    int b  = blockIdx.x >> 5;
    int pt = (blockIdx.x >> 2) & 7;
    int dt = blockIdx.x & 3;

    // load: thread (pl = t>>2, dseg = (t&3)*16): 16 d-floats of one p-row
    {
        int pl = t >> 2, dseg = (t & 3) * 16;
        const float4* src = (const float4*)(v + (((pt * 64 + pl) * 8 + b) << 8) + dt * 64 + dseg);
        float4 f0 = src[0], f1 = src[1], f2 = src[2], f3 = src[3];
        half_t hv[16] = {
            (half_t)f0.x,(half_t)f0.y,(half_t)f0.z,(half_t)f0.w,
            (half_t)f1.x,(half_t)f1.y,(half_t)f1.z,(half_t)f1.w,
            (half_t)f2.x,(half_t)f2.y,(half_t)f2.z,(half_t)f2.w,
            (half_t)f3.x,(half_t)f3.y,(half_t)f3.z,(half_t)f3.w };
#pragma unroll
        for (int u = 0; u < 16; ++u) lt[(dseg + u) * 66 + pl] = hv[u];
    }
    __syncthreads();
    // store: thread (dl = t>>2, pseg = (t&3)*16): 16 p-halfs contiguous
    {
        int dl = t >> 2, pseg = (t & 3) * 16;
        half8v h0 = *(const half8v*)(lt + dl * 66 + pseg);
        half8v h1 = *(const half8v*)(lt + dl * 66 + pseg + 8);
        half8v* dst = (half8v*)(vT16 + ((b * 256 + dt * 64 + dl) << 9) + pt * 64 + pseg);
        dst[0] = h0; dst[1] = h1;
    }
}

// ---------------- Wv1/Wv2T via MFMA: [4096,160] = v16 @ WT16B ---------------
// Outputs PRE-DOUBLED (fold the 2x of tanh's exp(2x) into the weights).
// Wv1 row-major [b][p][80] (pads 0); Wv2T transposed [b][h(80)][p].
__global__ __launch_bounds__(256) void wv12_kernel(
    const half_t* __restrict__ v16, const half_t* __restrict__ WT16B,
    float* __restrict__ Wv1, float* __restrict__ Wv2T)
{
    int tid = threadIdx.x;
    int lane = tid & 63, w = tid >> 6;
    int l15 = lane & 15, quad = lane >> 4;
    int r0 = blockIdx.x * 64 + w * 16;

    float4v acc[10];
#pragma unroll
    for (int nt = 0; nt < 10; ++nt) acc[nt] = (float4v){0.f, 0.f, 0.f, 0.f};

#pragma unroll
    for (int kt = 0; kt < 8; ++kt) {
        half8v a = *(const half8v*)(v16 + (r0 + l15) * 256 + kt * 32 + quad * 8);
#pragma unroll
        for (int nt = 0; nt < 10; ++nt) {
            half8v b = *(const half8v*)(WT16B + ((nt * 8 + kt) * 64 + lane) * 8);
            acc[nt] = __builtin_amdgcn_mfma_f32_16x16x32_f16(a, b, acc[nt], 0, 0, 0);
        }
    }
#pragma unroll
    for (int nt = 0; nt < 10; ++nt) {
        int col = nt * 16 + l15;
#pragma unroll
        for (int r = 0; r < 4; ++r) {
            int row = r0 + quad * 4 + r;
            int p = row >> 3, b = row & 7;
            int ob = (b * TP + p) * THP;
            float val2 = 2.0f * acc[nt][r];
            if (col < 75)       Wv1[ob + col] = val2;
            else if (col < 80)  { Wv1[ob + col] = 0.0f;
                                  Wv2T[(b * THP + col - 75) * TP + p] = val2; }
            else if (col < 150) Wv2T[(b * THP + col - 75) * TP + p] = val2;
            else if (col < 155) Wv2T[(b * THP + col - 75) * TP + p] = 0.0f;
        }
    }
}

// -------- scores -> softmax(i) -> a16[b][j][i] (f16) ------------------------
__global__ __launch_bounds__(256) void score_kernel(
    const float* __restrict__ Wv1, const float* __restrict__ Wv2T,
    const float* __restrict__ vw, half_t* __restrict__ a16)
{
    int tid = threadIdx.x;
    int b  = blockIdx.x >> 7;
    int j0 = (blockIdx.x & 127) * 4;
    __shared__ float wv1j[4 * THP];
    __shared__ float vws[THP];
    __shared__ float sc[4 * TP];

    if (tid < THP) vws[tid] = (tid < TH) ? vw[tid] : 0.0f;
    for (int e = tid; e < 4 * THP; e += 256) {
        int jj = e / THP, k = e - jj * THP;
        wv1j[e] = Wv1[(b * TP + j0 + jj) * THP + k];
    }
    __syncthreads();

    float Csum = 0.0f;
    {
        const float4* c4 = (const float4*)vws;
        for (int kk = 0; kk < 20; ++kk) { float4 c = c4[kk]; Csum += c.x + c.y + c.z + c.w; }
    }

    int i0 = tid, i1 = tid + 256;
    float acc0[4] = {0.f,0.f,0.f,0.f}, acc1[4] = {0.f,0.f,0.f,0.f};
    const float* wvt = Wv2T + b * THP * TP;
#pragma unroll
    for (int kt = 0; kt < 5; ++kt) {
        float r0v[16], r1v[16];
#pragma unroll
        for (int u = 0; u < 16; ++u) {
            const float* colp = wvt + (kt * 16 + u) * TP;
            r0v[u] = colp[i0];
            r1v[u] = colp[i1];
        }
        const float* cp = vws + kt * 16;
#pragma unroll
        for (int jj = 0; jj < 4; ++jj) {
            const float* w1 = wv1j + jj * THP + kt * 16;
            float s0 = 0.f, s1 = 0.f;
#pragma unroll
            for (int u = 0; u < 16; ++u) {
                float cu = cp[u], wu = w1[u];
                s0 += cu * fast_rcp(1.0f + __expf(r0v[u] + wu));
                s1 += cu * fast_rcp(1.0f + __expf(r1v[u] + wu));
            }
            acc0[jj] += s0; acc1[jj] += s1;
        }
    }
#pragma unroll
    for (int jj = 0; jj < 4; ++jj) {
        sc[jj * TP + i0] = Csum - 2.0f * acc0[jj];
        sc[jj * TP + i1] = Csum - 2.0f * acc1[jj];
    }
    __syncthreads();

    {
        int jj = tid >> 6, l = tid & 63;
        float m = -1e30f;
#pragma unroll
        for (int q = 0; q < 8; ++q) m = fmaxf(m, sc[jj * TP + l + q * 64]);
#pragma unroll
        for (int s = 32; s > 0; s >>= 1) m = fmaxf(m, __shfl_xor(m, s));
        float e[8];
        float sum = 0.0f;
#pragma unroll
        for (int q = 0; q < 8; ++q) { e[q] = __expf(sc[jj * TP + l + q * 64] - m); sum += e[q]; }
#pragma unroll
        for (int s = 32; s > 0; s >>= 1) sum += __shfl_xor(sum, s);
        float inv = fast_rcp(sum);
        half_t* arow = a16 + (b * TP + j0 + jj) * TP;
#pragma unroll
        for (int q = 0; q < 8; ++q) arow[l + q * 64] = (half_t)(e[q] * inv);
    }
}

// -------- context via MFMA: c[j,b,d] = sum_i a[b,j,i] * v[i,b,d] ------------
__global__ __launch_bounds__(256) void context_kernel(
    const half_t* __restrict__ a16, const half_t* __restrict__ vT16,
    half_t* __restrict__ g16)
{
    int tid = threadIdx.x;
    int lane = tid & 63, w = tid >> 6;
    int l15 = lane & 15, quad = lane >> 4;
    int b  = blockIdx.x >> 5;
    int mt = blockIdx.x & 31;

    const half_t* arow = a16 + (b * TP + mt * 16 + l15) * TP;
    const half_t* vbase = vT16 + ((b * 256) << 9);

    float4v acc[4];
#pragma unroll
    for (int nti = 0; nti < 4; ++nti) acc[nti] = (float4v){0.f, 0.f, 0.f, 0.f};

#pragma unroll 4
    for (int kt = 0; kt < 16; ++kt) {
        half8v a = *(const half8v*)(arow + kt * 32 + quad * 8);
#pragma unroll
        for (int nti = 0; nti < 4; ++nti) {
            int d = (w * 4 + nti) * 16 + l15;
            half8v bb = *(const half8v*)(vbase + (d << 9) + kt * 32 + quad * 8);
            acc[nti] = __builtin_amdgcn_mfma_f32_16x16x32_f16(a, bb, acc[nti], 0, 0, 0);
        }
    }
#pragma unroll
    for (int nti = 0; nti < 4; ++nti) {
        int d = (w * 4 + nti) * 16 + l15;
#pragma unroll
        for (int r = 0; r < 4; ++r) {
            int j = mt * 16 + quad * 4 + r;
            g16[(j * TB + b) * 512 + 256 + d] = (half_t)acc[nti][r];
        }
    }
}

// -------- MFMA gate (sigmoid(g Wg^T)*g) + GRU input projections -------------
__global__ __launch_bounds__(256, 1) void gatexp_kernel(
    const half_t* __restrict__ g16, const half_t* __restrict__ Wg16B,
    const half_t* __restrict__ Wih16B, const float* __restrict__ bihC,
    float* __restrict__ xpf, float* __restrict__ xpb)
{
    __shared__ half_t gA[32 * 520];      // rows padded to 520 halfs
    int tid = threadIdx.x;
    int r0 = blockIdx.x * 32;
    int lane = tid & 63, w = tid >> 6;
    int l15 = lane & 15, quad = lane >> 4;

    for (int e = tid; e < 2048; e += 256) {
        int row = e >> 6, c8 = e & 63;
        *(half8v*)(gA + row * 520 + c8 * 8) =
            *(const half8v*)(g16 + (r0 + row) * 512 + c8 * 8);
    }
    __syncthreads();

    float4v acc[2][8];
#pragma unroll
    for (int mi = 0; mi < 2; ++mi)
#pragma unroll
        for (int nti = 0; nti < 8; ++nti) acc[mi][nti] = (float4v){0.f, 0.f, 0.f, 0.f};

    for (int kt = 0; kt < 16; ++kt) {
        half8v a0 = *(const half8v*)(gA + l15 * 520 + kt * 32 + quad * 8);
        half8v a1 = *(const half8v*)(gA + (16 + l15) * 520 + kt * 32 + quad * 8);
#pragma unroll
        for (int nti = 0; nti < 8; ++nti) {
            half8v bb = *(const half8v*)(Wg16B + (((w * 8 + nti) * 16 + kt) * 64 + lane) * 8);
            acc[0][nti] = __builtin_amdgcn_mfma_f32_16x16x32_f16(a0, bb, acc[0][nti], 0, 0, 0);
            acc[1][nti] = __builtin_amdgcn_mfma_f32_16x16x32_f16(a1, bb, acc[1][nti], 0, 0, 0);
        }
    }
#pragma unroll
    for (int mi = 0; mi < 2; ++mi)
#pragma unroll
        for (int nti = 0; nti < 8; ++nti) {
            int colg = (w * 8 + nti) * 16 + l15;
#pragma unroll
            for (int r = 0; r < 4; ++r) {
                float gv = (float)gA[(mi * 16 + quad * 4 + r) * 520 + colg];
                acc[mi][nti][r] = fast_sigmoid(acc[mi][nti][r]) * gv;
            }
        }
    __syncthreads();
#pragma unroll
    for (int mi = 0; mi < 2; ++mi)
#pragma unroll
        for (int nti = 0; nti < 8; ++nti) {
            int colg = (w * 8 + nti) * 16 + l15;
#pragma unroll
            for (int r = 0; r < 4; ++r)
                gA[(mi * 16 + quad * 4 + r) * 520 + colg] = (half_t)acc[mi][nti][r];
        }
    __syncthreads();

    float4v c2[2][12];
#pragma unroll
    for (int mi = 0; mi < 2; ++mi)
#pragma unroll
        for (int nt2 = 0; nt2 < 12; ++nt2) {
            float bv = bihC[(w * 12 + nt2) * 16 + l15];
            c2[mi][nt2] = (float4v){bv, bv, bv, bv};
        }

    for (int kt = 0; kt < 16; ++kt) {
        half8v a0 = *(const half8v*)(gA + l15 * 520 + kt * 32 + quad * 8);
        half8v a1 = *(const half8v*)(gA + (16 + l15) * 520 + kt * 32 + quad * 8);
#pragma unroll
        for (int nt2 = 0; nt2 < 12; ++nt2) {
            half8v bb = *(const half8v*)(Wih16B + (((w * 12 + nt2) * 16 + kt) * 64 + lane) * 8);
            c2[0][nt2] = __builtin_amdgcn_mfma_f32_16x16x32_f16(a0, bb, c2[0][nt2], 0, 0, 0);
            c2[1][nt2] = __builtin_amdgcn_mfma_f32_16x16x32_f16(a1, bb, c2[1][nt2], 0, 0, 0);
        }
    }
#pragma unroll
    for (int mi = 0; mi < 2; ++mi)
#pragma unroll
        for (int nt2 = 0; nt2 < 12; ++nt2) {
            int col = (w * 12 + nt2) * 16 + l15;
            float* dst = (col < 384) ? (xpf + col) : (xpb + col - 384);
#pragma unroll
            for (int r = 0; r < 4; ++r)
                dst[(r0 + mi * 16 + quad * 4 + r) * 384] = c2[mi][nt2][r];
        }
}

// ---------------- GRU recurrence, one block per (dir, batch) ----------------
// R5 structure (291 us): 512 threads, (o = tid>>2, q = tid&3), w_hh f16 in
// VGPRs, h ping-pong f16 in LDS, fdot2, __syncthreads per step. NEW: quad
// reductions via DPP quad_perm adds (VALU pipe) instead of __shfl_xor
// (ds_bpermute, DS pipe) — frees ~290 cyc/step of DS pipe + shortens the
// serial chain.
__global__ __launch_bounds__(512) void gru_kernel(
    const float* __restrict__ xpf, const float* __restrict__ xpb,
    const half_t* __restrict__ whh16,
    const float* __restrict__ bhhf, const float* __restrict__ bhhb,
    float* __restrict__ out)
{
    int tid = threadIdx.x;
    int dir = blockIdx.x >> 3;
    int b   = blockIdx.x & 7;
    const float* xp  = dir ? xpb  : xpf;
    const float* bhh = dir ? bhhb : bhhf;
    const half_t* wbase = whh16 + dir * 3 * TO * TO;

    __shared__ __align__(16) half_t hb[2][TO];

    int o = tid >> 2, q = tid & 3;

    H8 wr[4], wz[4], wn[4];
    {
        const half8v* pr = (const half8v*)(wbase + (o)          * TO + q * 32);
        const half8v* pz = (const half8v*)(wbase + (TO + o)     * TO + q * 32);
        const half8v* pn = (const half8v*)(wbase + (2 * TO + o) * TO + q * 32);
#pragma unroll
        for (int kk = 0; kk < 4; ++kk) { wr[kk].v8 = pr[kk]; wz[kk].v8 = pz[kk]; wn[kk].v8 = pn[kk]; }
    }

    float br = 0.f, bz = 0.f, bn = 0.f, h = 0.f;
    float xr = 0.f, xz = 0.f, xn = 0.f;
    if (q == 0) {
        br = bhh[o]; bz = bhh[TO + o]; bn = bhh[2 * TO + o];
        int t0 = dir ? (TP - 1) : 0;
        const float* xpt = xp + (t0 * TB + b) * 384;
        xr = xpt[o]; xz = xpt[TO + o]; xn = xpt[2 * TO + o];
    }
    if (tid < TO) hb[0][tid] = (half_t)0.0f;
    __syncthreads();

    for (int s = 0; s < TP; ++s) {
        int t = dir ? (TP - 1 - s) : s;
        int cur = s & 1;
        const half8v* h8 = (const half8v*)(&hb[cur][q * 32]);
        H8 hv[4];
#pragma unroll
        for (int kk = 0; kk < 4; ++kk) hv[kk].v8 = h8[kk];

        float ar = 0.f, az = 0.f, an = 0.f;
#pragma unroll
        for (int kk = 0; kk < 4; ++kk) {
#pragma unroll
            for (int j = 0; j < 4; ++j) {
                half2v hp = hv[kk].v2[j];
                ar = fdot2h(wr[kk].v2[j], hp, ar);
                az = fdot2h(wz[kk].v2[j], hp, az);
                an = fdot2h(wn[kk].v2[j], hp, an);
            }
        }
        ar = quad_sum_dpp(ar);
        az = quad_sum_dpp(az);
        an = quad_sum_dpp(an);
        if (q == 0) {
            float r = fast_sigmoid(xr + ar + br);
            float z = fast_sigmoid(xz + az + bz);
            float n = fast_tanh(xn + r * (an + bn));
            h = (1.0f - z) * n + z * h;
            hb[cur ^ 1][o] = (half_t)h;
            out[(t * TB + b) * 256 + dir * TO + o] = h;
            int sn = (s + 1 < TP) ? s + 1 : s;
            int tn = dir ? (TP - 1 - sn) : sn;
            const float* xpt = xp + (tn * TB + b) * 384;
            xr = xpt[o]; xz = xpt[TO + o]; xn = xpt[2 * TO + o];
        }
        __syncthreads();
    }
}

extern "C" void kernel_launch(void* const* d_in, const int* in_sizes, int n_in,
                              void* d_out, int out_size, void* d_ws, size_t ws_size,
                              hipStream_t stream) {
    const float* v    = (const float*)d_in[0];
    const float* Wvp1 = (const float*)d_in[1];
    const float* Wvp2 = (const float*)d_in[2];
    const float* vw   = (const float*)d_in[3];
    const float* Wg   = (const float*)d_in[4];
    const float* wihf = (const float*)d_in[5];
    const float* whhf = (const float*)d_in[6];
    const float* bihf = (const float*)d_in[7];
    const float* bhhf = (const float*)d_in[8];
    const float* wihb = (const float*)d_in[9];
    const float* whhb = (const float*)d_in[10];
    const float* bihb = (const float*)d_in[11];
    const float* bhhb = (const float*)d_in[12];

    float* ws   = (float*)d_ws;
    float* bihC = ws;                    // 768 f32
    float* Wv1  = bihC + 768;            // 8*512*80 = 327680
    float* Wv2T = Wv1 + 327680;          // 8*80*512 = 327680 (transposed)
    float* xpf  = Wv2T + 327680;         // 4096*384 = 1572864
    float* xpb  = xpf + 1572864;         // 1572864
    half_t* g16    = (half_t*)(xpb + 1572864);  // 4096*512   = 2097152 halfs
    half_t* Wg16B  = g16 + 2097152;             // 262144
    half_t* Wih16B = Wg16B + 262144;            // 393216
    half_t* whh16  = Wih16B + 393216;           // 98304
    half_t* v16    = whh16 + 98304;             // 1048576
    half_t* WT16B  = v16 + 1048576;             // 40960
    half_t* vT16   = WT16B + 40960;             // 8*256*512  = 1048576
    half_t* a16    = vT16 + 1048576;            // 8*512*512  = 2097152
    float* out  = (float*)d_out;

    // prep idx total: 1048576+768+262144+393216+98304+40960 = 1843968 = 7203*256
    prep_kernel<<<7203, 256, 0, stream>>>(v, Wvp1, Wvp2, Wg, wihf, wihb, bihf, bihb,
                                          whhf, whhb, bihC, v16, g16,
                                          Wg16B, Wih16B, whh16, WT16B);
    vtrans_kernel<<<256, 256, 0, stream>>>(v, vT16);
    wv12_kernel<<<64, 256, 0, stream>>>(v16, WT16B, Wv1, Wv2T);
    score_kernel<<<1024, 256, 0, stream>>>(Wv1, Wv2T, vw, a16);
    context_kernel<<<256, 256, 0, stream>>>(a16, vT16, g16);
    gatexp_kernel<<<128, 256, 0, stream>>>(g16, Wg16B, Wih16B, bihC, xpf, xpb);
    gru_kernel<<<16, 512, 0, stream>>>(xpf, xpb, whh16, bhhf, bhhb, out);
}

// Round 10
// 476.488 us; speedup vs baseline: 1.6266x; 1.0047x over previous
//
#include <hip/hip_runtime.h>

// Problem constants
#define TP 512   // passage length
#define TB 8     // batch
#define TD 256   // input size
#define TH 75    // attn hidden
#define THP 80   // padded attn hidden (float4-friendly, pads zeroed)
#define TO 128   // GRU hidden

typedef _Float16 half_t;
typedef _Float16 half2v __attribute__((ext_vector_type(2)));
typedef _Float16 half4v __attribute__((ext_vector_type(4)));
typedef _Float16 half8v __attribute__((ext_vector_type(8)));
typedef float    float4v __attribute__((ext_vector_type(4)));

union H8 { half8v v8; half2v v2[4]; };

__device__ __forceinline__ float fast_rcp(float x) { return __builtin_amdgcn_rcpf(x); }
__device__ __forceinline__ float fast_tanh(float x) {
    return 1.0f - 2.0f * fast_rcp(1.0f + __expf(2.0f * x));
}
__device__ __forceinline__ float fast_sigmoid(float x) {
    return fast_rcp(1.0f + __expf(-x));
}
__device__ __forceinline__ float fdot2h(half2v a, half2v b, float c) {
#if __has_builtin(__builtin_amdgcn_fdot2)
    return __builtin_amdgcn_fdot2(a, b, c, false);
#else
    return c + (float)a[0] * (float)b[0] + (float)a[1] * (float)b[1];
#endif
}
// quad butterfly sum via DPP (VALU pipe, not DS): after this all 4 lanes of
// each quad hold the 4-lane sum. quad_perm [1,0,3,2]=0xB1, [2,3,0,1]=0x4E.
__device__ __forceinline__ float quad_sum_dpp(float v) {
    int i1 = __builtin_amdgcn_update_dpp(0, __builtin_bit_cast(int, v), 0xB1, 0xF, 0xF, true);
    v = v + __builtin_bit_cast(float, i1);
    int i2 = __builtin_amdgcn_update_dpp(0, __builtin_bit_cast(int, v), 0x4E, 0xF, 0xF, true);
    return v + __builtin_bit_cast(float, i2);
}

// ---------------- prep: f16 casts, B-frag swizzles, whh16 -------------------
// B-frag layout (mfma_f32_16x16x32_f16): [nt][kt][lane][j] halfs with
// B[k = kt*32 + (lane>>4)*8 + j][n = nt*16 + (lane&15)]  (verified R5/R6).
__global__ __launch_bounds__(256) void prep_kernel(
    const float* __restrict__ v,
    const float* __restrict__ Wvp1, const float* __restrict__ Wvp2,
    const float* __restrict__ Wg,   const float* __restrict__ wihf,
    const float* __restrict__ wihb, const float* __restrict__ bihf,
    const float* __restrict__ bihb, const float* __restrict__ whhf,
    const float* __restrict__ whhb,
    float* __restrict__ bihC,
    half_t* __restrict__ v16, half_t* __restrict__ g16,
    half_t* __restrict__ Wg16B, half_t* __restrict__ Wih16B,
    half_t* __restrict__ whh16, half_t* __restrict__ WT16B)
{
    int idx = blockIdx.x * 256 + threadIdx.x;
    if (idx < 1048576) {                        // v cast (coalesced)
        half_t val = (half_t)v[idx];
        v16[idx] = val;                          // [p*8+b][d]
        int row = idx >> 8, d = idx & 255;       // row = p*8+b
        g16[row * 512 + d] = val;                // g first half = v
        return;
    }
    idx -= 1048576;
    if (idx < 768) { bihC[idx] = (idx < 384) ? bihf[idx] : bihb[idx - 384]; return; }
    idx -= 768;
    if (idx < 262144) {                         // Wg16B (nt 0..31)
        int j = idx & 7, lane = (idx >> 3) & 63, kt = (idx >> 9) & 15, nt = idx >> 13;
        int o = nt * 16 + (lane & 15);
        int k = kt * 32 + ((lane >> 4) << 3) + j;
        Wg16B[idx] = (half_t)Wg[o * 512 + k];
        return;
    }
    idx -= 262144;
    if (idx < 393216) {                         // Wih16B (nt 0..47, o<384 fwd)
        int j = idx & 7, lane = (idx >> 3) & 63, kt = (idx >> 9) & 15, nt = idx >> 13;
        int o = nt * 16 + (lane & 15);
        int k = kt * 32 + ((lane >> 4) << 3) + j;
        Wih16B[idx] = (half_t)((o < 384) ? wihf[o * 512 + k] : wihb[(o - 384) * 512 + k]);
        return;
    }
    idx -= 393216;
    if (idx < 98304) {                          // whh16[dir][(g*128+o)*128+k]
        int d = idx / 49152, i = idx - d * 49152;
        whh16[idx] = (half_t)(d ? whhb[i] : whhf[i]);
        return;
    }
    idx -= 98304;
    if (idx < 40960) {                          // WT16B (nt 0..9): [Wvp1;Wvp2]
        int j = idx & 7, lane = (idx >> 3) & 63, kt = (idx >> 9) & 7, nt = idx >> 12;
        int o = nt * 16 + (lane & 15);
        int k = kt * 32 + ((lane >> 4) << 3) + j;
        float vv = 0.0f;
        if (o < 75)       vv = Wvp1[o * 256 + k];
        else if (o < 150) vv = Wvp2[(o - 75) * 256 + k];
        WT16B[idx] = (half_t)vv;
    }
}

// ---------------- vT16[b][d][p] tiled transpose (coalesced R/W) -------------
// grid 256 = b(8) x pt(8) x dt(4); 64x64 f32->f16 tile through LDS.
__global__ __launch_bounds__(256) void vtrans_kernel(
    const float* __restrict__ v, half_t* __restrict__ vT16)
{
    __shared__ half_t lt[64 * 66];   // [d_local][p_local], stride 66
    int t = threadIdx.x;
    int b  = blockIdx.x >> 5;
    int pt = (blockIdx.x >> 2) & 7;
    int dt = blockIdx.x & 3;

    {
        int pl = t >> 2, dseg = (t & 3) * 16;
        const float4* src = (const float4*)(v + (((pt * 64 + pl) * 8 + b) << 8) + dt * 64 + dseg);
        float4 f0 = src[0], f1 = src[1], f2 = src[2], f3 = src[3];
        half_t hv[16] = {
            (half_t)f0.x,(half_t)f0.y,(half_t)f0.z,(half_t)f0.w,
            (half_t)f1.x,(half_t)f1.y,(half_t)f1.z,(half_t)f1.w,
            (half_t)f2.x,(half_t)f2.y,(half_t)f2.z,(half_t)f2.w,
            (half_t)f3.x,(half_t)f3.y,(half_t)f3.z,(half_t)f3.w };
#pragma unroll
        for (int u = 0; u < 16; ++u) lt[(dseg + u) * 66 + pl] = hv[u];
    }
    __syncthreads();
    {
        int dl = t >> 2, pseg = (t & 3) * 16;
        half8v h0 = *(const half8v*)(lt + dl * 66 + pseg);
        half8v h1 = *(const half8v*)(lt + dl * 66 + pseg + 8);
        half8v* dst = (half8v*)(vT16 + ((b * 256 + dt * 64 + dl) << 9) + pt * 64 + pseg);
        dst[0] = h0; dst[1] = h1;
    }
}

// ---------------- Wv1/Wv2T via MFMA: [4096,160] = v16 @ WT16B ---------------
// Outputs PRE-DOUBLED (fold the 2x of tanh's exp(2x) into the weights).
// Wv1 row-major [b][p][80] (pads 0); Wv2T transposed [b][h(80)][p].
__global__ __launch_bounds__(256) void wv12_kernel(
    const half_t* __restrict__ v16, const half_t* __restrict__ WT16B,
    float* __restrict__ Wv1, float* __restrict__ Wv2T)
{
    int tid = threadIdx.x;
    int lane = tid & 63, w = tid >> 6;
    int l15 = lane & 15, quad = lane >> 4;
    int r0 = blockIdx.x * 64 + w * 16;

    float4v acc[10];
#pragma unroll
    for (int nt = 0; nt < 10; ++nt) acc[nt] = (float4v){0.f, 0.f, 0.f, 0.f};

#pragma unroll
    for (int kt = 0; kt < 8; ++kt) {
        half8v a = *(const half8v*)(v16 + (r0 + l15) * 256 + kt * 32 + quad * 8);
#pragma unroll
        for (int nt = 0; nt < 10; ++nt) {
            half8v b = *(const half8v*)(WT16B + ((nt * 8 + kt) * 64 + lane) * 8);
            acc[nt] = __builtin_amdgcn_mfma_f32_16x16x32_f16(a, b, acc[nt], 0, 0, 0);
        }
    }
#pragma unroll
    for (int nt = 0; nt < 10; ++nt) {
        int col = nt * 16 + l15;
#pragma unroll
        for (int r = 0; r < 4; ++r) {
            int row = r0 + quad * 4 + r;
            int p = row >> 3, b = row & 7;
            int ob = (b * TP + p) * THP;
            float val2 = 2.0f * acc[nt][r];
            if (col < 75)       Wv1[ob + col] = val2;
            else if (col < 80)  { Wv1[ob + col] = 0.0f;
                                  Wv2T[(b * THP + col - 75) * TP + p] = val2; }
            else if (col < 150) Wv2T[(b * THP + col - 75) * TP + p] = val2;
            else if (col < 155) Wv2T[(b * THP + col - 75) * TP + p] = 0.0f;
        }
    }
}

// -------- scores -> softmax(i) -> a16[b][j][i] (f16) ------------------------
__global__ __launch_bounds__(256) void score_kernel(
    const float* __restrict__ Wv1, const float* __restrict__ Wv2T,
    const float* __restrict__ vw, half_t* __restrict__ a16)
{
    int tid = threadIdx.x;
    int b  = blockIdx.x >> 7;
    int j0 = (blockIdx.x & 127) * 4;
    __shared__ float wv1j[4 * THP];
    __shared__ float vws[THP];
    __shared__ float sc[4 * TP];

    if (tid < THP) vws[tid] = (tid < TH) ? vw[tid] : 0.0f;
    for (int e = tid; e < 4 * THP; e += 256) {
        int jj = e / THP, k = e - jj * THP;
        wv1j[e] = Wv1[(b * TP + j0 + jj) * THP + k];
    }
    __syncthreads();

    float Csum = 0.0f;
    {
        const float4* c4 = (const float4*)vws;
        for (int kk = 0; kk < 20; ++kk) { float4 c = c4[kk]; Csum += c.x + c.y + c.z + c.w; }
    }

    int i0 = tid, i1 = tid + 256;
    float acc0[4] = {0.f,0.f,0.f,0.f}, acc1[4] = {0.f,0.f,0.f,0.f};
    const float* wvt = Wv2T + b * THP * TP;
#pragma unroll
    for (int kt = 0; kt < 5; ++kt) {
        float r0v[16], r1v[16];
#pragma unroll
        for (int u = 0; u < 16; ++u) {
            const float* colp = wvt + (kt * 16 + u) * TP;
            r0v[u] = colp[i0];
            r1v[u] = colp[i1];
        }
        const float* cp = vws + kt * 16;
#pragma unroll
        for (int jj = 0; jj < 4; ++jj) {
            const float* w1 = wv1j + jj * THP + kt * 16;
            float s0 = 0.f, s1 = 0.f;
#pragma unroll
            for (int u = 0; u < 16; ++u) {
                float cu = cp[u], wu = w1[u];
                s0 += cu * fast_rcp(1.0f + __expf(r0v[u] + wu));
                s1 += cu * fast_rcp(1.0f + __expf(r1v[u] + wu));
            }
            acc0[jj] += s0; acc1[jj] += s1;
        }
    }
#pragma unroll
    for (int jj = 0; jj < 4; ++jj) {
        sc[jj * TP + i0] = Csum - 2.0f * acc0[jj];
        sc[jj * TP + i1] = Csum - 2.0f * acc1[jj];
    }
    __syncthreads();

    {
        int jj = tid >> 6, l = tid & 63;
        float m = -1e30f;
#pragma unroll
        for (int q = 0; q < 8; ++q) m = fmaxf(m, sc[jj * TP + l + q * 64]);
#pragma unroll
        for (int s = 32; s > 0; s >>= 1) m = fmaxf(m, __shfl_xor(m, s));
        float e[8];
        float sum = 0.0f;
#pragma unroll
        for (int q = 0; q < 8; ++q) { e[q] = __expf(sc[jj * TP + l + q * 64] - m); sum += e[q]; }
#pragma unroll
        for (int s = 32; s > 0; s >>= 1) sum += __shfl_xor(sum, s);
        float inv = fast_rcp(sum);
        half_t* arow = a16 + (b * TP + j0 + jj) * TP;
#pragma unroll
        for (int q = 0; q < 8; ++q) arow[l + q * 64] = (half_t)(e[q] * inv);
    }
}

// -------- context via MFMA: c[j,b,d] = sum_i a[b,j,i] * v[i,b,d] ------------
__global__ __launch_bounds__(256) void context_kernel(
    const half_t* __restrict__ a16, const half_t* __restrict__ vT16,
    half_t* __restrict__ g16)
{
    int tid = threadIdx.x;
    int lane = tid & 63, w = tid >> 6;
    int l15 = lane & 15, quad = lane >> 4;
    int b  = blockIdx.x >> 5;
    int mt = blockIdx.x & 31;

    const half_t* arow = a16 + (b * TP + mt * 16 + l15) * TP;
    const half_t* vbase = vT16 + ((b * 256) << 9);

    float4v acc[4];
#pragma unroll
    for (int nti = 0; nti < 4; ++nti) acc[nti] = (float4v){0.f, 0.f, 0.f, 0.f};

#pragma unroll 4
    for (int kt = 0; kt < 16; ++kt) {
        half8v a = *(const half8v*)(arow + kt * 32 + quad * 8);
#pragma unroll
        for (int nti = 0; nti < 4; ++nti) {
            int d = (w * 4 + nti) * 16 + l15;
            half8v bb = *(const half8v*)(vbase + (d << 9) + kt * 32 + quad * 8);
            acc[nti] = __builtin_amdgcn_mfma_f32_16x16x32_f16(a, bb, acc[nti], 0, 0, 0);
        }
    }
#pragma unroll
    for (int nti = 0; nti < 4; ++nti) {
        int d = (w * 4 + nti) * 16 + l15;
#pragma unroll
        for (int r = 0; r < 4; ++r) {
            int j = mt * 16 + quad * 4 + r;
            g16[(j * TB + b) * 512 + 256 + d] = (half_t)acc[nti][r];
        }
    }
}

// -------- MFMA gate (sigmoid(g Wg^T)*g) + GRU input projections -------------
__global__ __launch_bounds__(256, 1) void gatexp_kernel(
    const half_t* __restrict__ g16, const half_t* __restrict__ Wg16B,
    const half_t* __restrict__ Wih16B, const float* __restrict__ bihC,
    float* __restrict__ xpf, float* __restrict__ xpb)
{
    __shared__ half_t gA[32 * 520];      // rows padded to 520 halfs
    int tid = threadIdx.x;
    int r0 = blockIdx.x * 32;
    int lane = tid & 63, w = tid >> 6;
    int l15 = lane & 15, quad = lane >> 4;

    for (int e = tid; e < 2048; e += 256) {
        int row = e >> 6, c8 = e & 63;
        *(half8v*)(gA + row * 520 + c8 * 8) =
            *(const half8v*)(g16 + (r0 + row) * 512 + c8 * 8);
    }
    __syncthreads();

    float4v acc[2][8];
#pragma unroll
    for (int mi = 0; mi < 2; ++mi)
#pragma unroll
        for (int nti = 0; nti < 8; ++nti) acc[mi][nti] = (float4v){0.f, 0.f, 0.f, 0.f};

    for (int kt = 0; kt < 16; ++kt) {
        half8v a0 = *(const half8v*)(gA + l15 * 520 + kt * 32 + quad * 8);
        half8v a1 = *(const half8v*)(gA + (16 + l15) * 520 + kt * 32 + quad * 8);
#pragma unroll
        for (int nti = 0; nti < 8; ++nti) {
            half8v bb = *(const half8v*)(Wg16B + (((w * 8 + nti) * 16 + kt) * 64 + lane) * 8);
            acc[0][nti] = __builtin_amdgcn_mfma_f32_16x16x32_f16(a0, bb, acc[0][nti], 0, 0, 0);
            acc[1][nti] = __builtin_amdgcn_mfma_f32_16x16x32_f16(a1, bb, acc[1][nti], 0, 0, 0);
        }
    }
#pragma unroll
    for (int mi = 0; mi < 2; ++mi)
#pragma unroll
        for (int nti = 0; nti < 8; ++nti) {
            int colg = (w * 8 + nti) * 16 + l15;
#pragma unroll
            for (int r = 0; r < 4; ++r) {
                float gv = (float)gA[(mi * 16 + quad * 4 + r) * 520 + colg];
                acc[mi][nti][r] = fast_sigmoid(acc[mi][nti][r]) * gv;
            }
        }
    __syncthreads();
#pragma unroll
    for (int mi = 0; mi < 2; ++mi)
#pragma unroll
        for (int nti = 0; nti < 8; ++nti) {
            int colg = (w * 8 + nti) * 16 + l15;
#pragma unroll
            for (int r = 0; r < 4; ++r)
                gA[(mi * 16 + quad * 4 + r) * 520 + colg] = (half_t)acc[mi][nti][r];
        }
    __syncthreads();

    float4v c2[2][12];
#pragma unroll
    for (int mi = 0; mi < 2; ++mi)
#pragma unroll
        for (int nt2 = 0; nt2 < 12; ++nt2) {
            float bv = bihC[(w * 12 + nt2) * 16 + l15];
            c2[mi][nt2] = (float4v){bv, bv, bv, bv};
        }

    for (int kt = 0; kt < 16; ++kt) {
        half8v a0 = *(const half8v*)(gA + l15 * 520 + kt * 32 + quad * 8);
        half8v a1 = *(const half8v*)(gA + (16 + l15) * 520 + kt * 32 + quad * 8);
#pragma unroll
        for (int nt2 = 0; nt2 < 12; ++nt2) {
            half8v bb = *(const half8v*)(Wih16B + (((w * 12 + nt2) * 16 + kt) * 64 + lane) * 8);
            c2[0][nt2] = __builtin_amdgcn_mfma_f32_16x16x32_f16(a0, bb, c2[0][nt2], 0, 0, 0);
            c2[1][nt2] = __builtin_amdgcn_mfma_f32_16x16x32_f16(a1, bb, c2[1][nt2], 0, 0, 0);
        }
    }
#pragma unroll
    for (int mi = 0; mi < 2; ++mi)
#pragma unroll
        for (int nt2 = 0; nt2 < 12; ++nt2) {
            int col = (w * 12 + nt2) * 16 + l15;
            float* dst = (col < 384) ? (xpf + col) : (xpb + col - 384);
#pragma unroll
            for (int r = 0; r < 4; ++r)
                dst[(r0 + mi * 16 + quad * 4 + r) * 384] = c2[mi][nt2][r];
        }
}

// ---------------- GRU recurrence, one block per (dir, batch) ----------------
// R9 structure (267 us) + macro-step global-traffic batching: the per-step
// __syncthreads drains vmcnt(0), so every step paid the out-store ack plus
// the xp prefetch latency. Now all 24 xp loads for 8 steps are issued once
// per macro-step and 8 h-values are held in registers and stored once per
// macro-step -> 7 of 8 barriers drain nothing outstanding.
__global__ __launch_bounds__(512) void gru_kernel(
    const float* __restrict__ xpf, const float* __restrict__ xpb,
    const half_t* __restrict__ whh16,
    const float* __restrict__ bhhf, const float* __restrict__ bhhb,
    float* __restrict__ out)
{
    int tid = threadIdx.x;
    int dir = blockIdx.x >> 3;
    int b   = blockIdx.x & 7;
    const float* xp  = dir ? xpb  : xpf;
    const float* bhh = dir ? bhhb : bhhf;
    const half_t* wbase = whh16 + dir * 3 * TO * TO;

    __shared__ __align__(16) half_t hb[2][TO];

    int o = tid >> 2, q = tid & 3;

    H8 wr[4], wz[4], wn[4];
    {
        const half8v* pr = (const half8v*)(wbase + (o)          * TO + q * 32);
        const half8v* pz = (const half8v*)(wbase + (TO + o)     * TO + q * 32);
        const half8v* pn = (const half8v*)(wbase + (2 * TO + o) * TO + q * 32);
#pragma unroll
        for (int kk = 0; kk < 4; ++kk) { wr[kk].v8 = pr[kk]; wz[kk].v8 = pz[kk]; wn[kk].v8 = pn[kk]; }
    }

    float br = 0.f, bz = 0.f, bn = 0.f, h = 0.f;
    if (q == 0) {
        br = bhh[o]; bz = bhh[TO + o]; bn = bhh[2 * TO + o];
    }
    if (tid < TO) hb[0][tid] = (half_t)0.0f;
    __syncthreads();

    float xrv[8], xzv[8], xnv[8], hist[8];

    for (int S = 0; S < TP; S += 8) {
        // batch-issue 24 xp loads for steps S..S+7 (q==0 lanes)
        if (q == 0) {
#pragma unroll
            for (int u = 0; u < 8; ++u) {
                int s = S + u;
                int tn = dir ? (TP - 1 - s) : s;
                const float* xpt = xp + (tn * TB + b) * 384;
                xrv[u] = xpt[o]; xzv[u] = xpt[TO + o]; xnv[u] = xpt[2 * TO + o];
            }
        }
#pragma unroll
        for (int u = 0; u < 8; ++u) {
            int s = S + u;
            int cur = s & 1;
            const half8v* h8 = (const half8v*)(&hb[cur][q * 32]);
            H8 hv[4];
#pragma unroll
            for (int kk = 0; kk < 4; ++kk) hv[kk].v8 = h8[kk];

            float ar = 0.f, az = 0.f, an = 0.f;
#pragma unroll
            for (int kk = 0; kk < 4; ++kk) {
#pragma unroll
                for (int j = 0; j < 4; ++j) {
                    half2v hp = hv[kk].v2[j];
                    ar = fdot2h(wr[kk].v2[j], hp, ar);
                    az = fdot2h(wz[kk].v2[j], hp, az);
                    an = fdot2h(wn[kk].v2[j], hp, an);
                }
            }
            ar = quad_sum_dpp(ar);
            az = quad_sum_dpp(az);
            an = quad_sum_dpp(an);
            if (q == 0) {
                float r = fast_sigmoid(xrv[u] + ar + br);
                float z = fast_sigmoid(xzv[u] + az + bz);
                float n = fast_tanh(xnv[u] + r * (an + bn));
                h = (1.0f - z) * n + z * h;
                hb[cur ^ 1][o] = (half_t)h;
                hist[u] = h;
            }
            __syncthreads();
        }
        // batch the out-stores (acks amortized over the next macro-step)
        if (q == 0) {
#pragma unroll
            for (int u = 0; u < 8; ++u) {
                int s = S + u;
                int t = dir ? (TP - 1 - s) : s;
                out[(t * TB + b) * 256 + dir * TO + o] = hist[u];
            }
        }
    }
}

extern "C" void kernel_launch(void* const* d_in, const int* in_sizes, int n_in,
                              void* d_out, int out_size, void* d_ws, size_t ws_size,
                              hipStream_t stream) {
    const float* v    = (const float*)d_in[0];
    const float* Wvp1 = (const float*)d_in[1];
    const float* Wvp2 = (const float*)d_in[2];
    const float* vw   = (const float*)d_in[3];
    const float* Wg   = (const float*)d_in[4];
    const float* wihf = (const float*)d_in[5];
    const float* whhf = (const float*)d_in[6];
    const float* bihf = (const float*)d_in[7];
    const float* bhhf = (const float*)d_in[8];
    const float* wihb = (const float*)d_in[9];
    const float* whhb = (const float*)d_in[10];
    const float* bihb = (const float*)d_in[11];
    const float* bhhb = (const float*)d_in[12];

    float* ws   = (float*)d_ws;
    float* bihC = ws;                    // 768 f32
    float* Wv1  = bihC + 768;            // 8*512*80 = 327680
    float* Wv2T = Wv1 + 327680;          // 8*80*512 = 327680 (transposed)
    float* xpf  = Wv2T + 327680;         // 4096*384 = 1572864
    float* xpb  = xpf + 1572864;         // 1572864
    half_t* g16    = (half_t*)(xpb + 1572864);  // 4096*512   = 2097152 halfs
    half_t* Wg16B  = g16 + 2097152;             // 262144
    half_t* Wih16B = Wg16B + 262144;            // 393216
    half_t* whh16  = Wih16B + 393216;           // 98304
    half_t* v16    = whh16 + 98304;             // 1048576
    half_t* WT16B  = v16 + 1048576;             // 40960
    half_t* vT16   = WT16B + 40960;             // 8*256*512  = 1048576
    half_t* a16    = vT16 + 1048576;            // 8*512*512  = 2097152
    float* out  = (float*)d_out;

    // prep idx total: 1048576+768+262144+393216+98304+40960 = 1843968 = 7203*256
    prep_kernel<<<7203, 256, 0, stream>>>(v, Wvp1, Wvp2, Wg, wihf, wihb, bihf, bihb,
                                          whhf, whhb, bihC, v16, g16,
                                          Wg16B, Wih16B, whh16, WT16B);
    vtrans_kernel<<<256, 256, 0, stream>>>(v, vT16);
    wv12_kernel<<<64, 256, 0, stream>>>(v16, WT16B, Wv1, Wv2T);
    score_kernel<<<1024, 256, 0, stream>>>(Wv1, Wv2T, vw, a16);
    context_kernel<<<256, 256, 0, stream>>>(a16, vT16, g16);
    gatexp_kernel<<<128, 256, 0, stream>>>(g16, Wg16B, Wih16B, bihC, xpf, xpb);
    gru_kernel<<<16, 512, 0, stream>>>(xpf, xpb, whh16, bhhf, bhhb, out);
}

// Round 12
// 441.196 us; speedup vs baseline: 1.7567x; 1.0800x over previous
//
#include <hip/hip_runtime.h>

// Problem constants
#define TP 512   // passage length
#define TB 8     // batch
#define TD 256   // input size
#define TH 75    // attn hidden
#define THP 80   // padded attn hidden (float4-friendly, pads zeroed)
#define TO 128   // GRU hidden

typedef _Float16 half_t;
typedef _Float16 half2v __attribute__((ext_vector_type(2)));
typedef _Float16 half4v __attribute__((ext_vector_type(4)));
typedef _Float16 half8v __attribute__((ext_vector_type(8)));
typedef float    float4v __attribute__((ext_vector_type(4)));

union H8 { half8v v8; half2v v2[4]; };

__device__ __forceinline__ float fast_rcp(float x) { return __builtin_amdgcn_rcpf(x); }
__device__ __forceinline__ float fast_tanh(float x) {
    return 1.0f - 2.0f * fast_rcp(1.0f + __expf(2.0f * x));
}
__device__ __forceinline__ float fast_sigmoid(float x) {
    return fast_rcp(1.0f + __expf(-x));
}
__device__ __forceinline__ float fdot2h(half2v a, half2v b, float c) {
#if __has_builtin(__builtin_amdgcn_fdot2)
    return __builtin_amdgcn_fdot2(a, b, c, false);
#else
    return c + (float)a[0] * (float)b[0] + (float)a[1] * (float)b[1];
#endif
}
// adjacent-lane (xor-1) butterfly sum via DPP quad_perm [1,0,3,2] (VALU pipe).
__device__ __forceinline__ float pair_sum_dpp(float v) {
    int i1 = __builtin_amdgcn_update_dpp(0, __builtin_bit_cast(int, v), 0xB1, 0xF, 0xF, true);
    return v + __builtin_bit_cast(float, i1);
}

// ---------------- prep: f16 casts, B-frag swizzles, whh16 -------------------
// B-frag layout (mfma_f32_16x16x32_f16): [nt][kt][lane][j] halfs with
// B[k = kt*32 + (lane>>4)*8 + j][n = nt*16 + (lane&15)]  (verified R5/R6).
__global__ __launch_bounds__(256) void prep_kernel(
    const float* __restrict__ v,
    const float* __restrict__ Wvp1, const float* __restrict__ Wvp2,
    const float* __restrict__ Wg,   const float* __restrict__ wihf,
    const float* __restrict__ wihb, const float* __restrict__ bihf,
    const float* __restrict__ bihb, const float* __restrict__ whhf,
    const float* __restrict__ whhb,
    float* __restrict__ bihC,
    half_t* __restrict__ v16, half_t* __restrict__ g16,
    half_t* __restrict__ Wg16B, half_t* __restrict__ Wih16B,
    half_t* __restrict__ whh16, half_t* __restrict__ WT16B)
{
    int idx = blockIdx.x * 256 + threadIdx.x;
    if (idx < 1048576) {                        // v cast (coalesced)
        half_t val = (half_t)v[idx];
        v16[idx] = val;                          // [p*8+b][d]
        int row = idx >> 8, d = idx & 255;       // row = p*8+b
        g16[row * 512 + d] = val;                // g first half = v
        return;
    }
    idx -= 1048576;
    if (idx < 768) { bihC[idx] = (idx < 384) ? bihf[idx] : bihb[idx - 384]; return; }
    idx -= 768;
    if (idx < 262144) {                         // Wg16B (nt 0..31)
        int j = idx & 7, lane = (idx >> 3) & 63, kt = (idx >> 9) & 15, nt = idx >> 13;
        int o = nt * 16 + (lane & 15);
        int k = kt * 32 + ((lane >> 4) << 3) + j;
        Wg16B[idx] = (half_t)Wg[o * 512 + k];
        return;
    }
    idx -= 262144;
    if (idx < 393216) {                         // Wih16B (nt 0..47, o<384 fwd)
        int j = idx & 7, lane = (idx >> 3) & 63, kt = (idx >> 9) & 15, nt = idx >> 13;
        int o = nt * 16 + (lane & 15);
        int k = kt * 32 + ((lane >> 4) << 3) + j;
        Wih16B[idx] = (half_t)((o < 384) ? wihf[o * 512 + k] : wihb[(o - 384) * 512 + k]);
        return;
    }
    idx -= 393216;
    if (idx < 98304) {                          // whh16[dir][(g*128+o)*128+k]
        int d = idx / 49152, i = idx - d * 49152;
        whh16[idx] = (half_t)(d ? whhb[i] : whhf[i]);
        return;
    }
    idx -= 98304;
    if (idx < 40960) {                          // WT16B (nt 0..9): [Wvp1;Wvp2]
        int j = idx & 7, lane = (idx >> 3) & 63, kt = (idx >> 9) & 7, nt = idx >> 12;
        int o = nt * 16 + (lane & 15);
        int k = kt * 32 + ((lane >> 4) << 3) + j;
        float vv = 0.0f;
        if (o < 75)       vv = Wvp1[o * 256 + k];
        else if (o < 150) vv = Wvp2[(o - 75) * 256 + k];
        WT16B[idx] = (half_t)vv;
    }
}

// ---------------- vT16[b][d][p] tiled transpose (coalesced R/W) -------------
__global__ __launch_bounds__(256) void vtrans_kernel(
    const float* __restrict__ v, half_t* __restrict__ vT16)
{
    __shared__ half_t lt[64 * 66];   // [d_local][p_local], stride 66
    int t = threadIdx.x;
    int b  = blockIdx.x >> 5;
    int pt = (blockIdx.x >> 2) & 7;
    int dt = blockIdx.x & 3;

    {
        int pl = t >> 2, dseg = (t & 3) * 16;
        const float4* src = (const float4*)(v + (((pt * 64 + pl) * 8 + b) << 8) + dt * 64 + dseg);
        float4 f0 = src[0], f1 = src[1], f2 = src[2], f3 = src[3];
        half_t hv[16] = {
            (half_t)f0.x,(half_t)f0.y,(half_t)f0.z,(half_t)f0.w,
            (half_t)f1.x,(half_t)f1.y,(half_t)f1.z,(half_t)f1.w,
            (half_t)f2.x,(half_t)f2.y,(half_t)f2.z,(half_t)f2.w,
            (half_t)f3.x,(half_t)f3.y,(half_t)f3.z,(half_t)f3.w };
#pragma unroll
        for (int u = 0; u < 16; ++u) lt[(dseg + u) * 66 + pl] = hv[u];
    }
    __syncthreads();
    {
        int dl = t >> 2, pseg = (t & 3) * 16;
        half8v h0 = *(const half8v*)(lt + dl * 66 + pseg);
        half8v h1 = *(const half8v*)(lt + dl * 66 + pseg + 8);
        half8v* dst = (half8v*)(vT16 + ((b * 256 + dt * 64 + dl) << 9) + pt * 64 + pseg);
        dst[0] = h0; dst[1] = h1;
    }
}

// ---------------- Wv1/Wv2T via MFMA: [4096,160] = v16 @ WT16B ---------------
__global__ __launch_bounds__(256) void wv12_kernel(
    const half_t* __restrict__ v16, const half_t* __restrict__ WT16B,
    float* __restrict__ Wv1, float* __restrict__ Wv2T)
{
    int tid = threadIdx.x;
    int lane = tid & 63, w = tid >> 6;
    int l15 = lane & 15, quad = lane >> 4;
    int r0 = blockIdx.x * 64 + w * 16;

    float4v acc[10];
#pragma unroll
    for (int nt = 0; nt < 10; ++nt) acc[nt] = (float4v){0.f, 0.f, 0.f, 0.f};

#pragma unroll
    for (int kt = 0; kt < 8; ++kt) {
        half8v a = *(const half8v*)(v16 + (r0 + l15) * 256 + kt * 32 + quad * 8);
#pragma unroll
        for (int nt = 0; nt < 10; ++nt) {
            half8v b = *(const half8v*)(WT16B + ((nt * 8 + kt) * 64 + lane) * 8);
            acc[nt] = __builtin_amdgcn_mfma_f32_16x16x32_f16(a, b, acc[nt], 0, 0, 0);
        }
    }
#pragma unroll
    for (int nt = 0; nt < 10; ++nt) {
        int col = nt * 16 + l15;
#pragma unroll
        for (int r = 0; r < 4; ++r) {
            int row = r0 + quad * 4 + r;
            int p = row >> 3, b = row & 7;
            int ob = (b * TP + p) * THP;
            float val2 = 2.0f * acc[nt][r];
            if (col < 75)       Wv1[ob + col] = val2;
            else if (col < 80)  { Wv1[ob + col] = 0.0f;
                                  Wv2T[(b * THP + col - 75) * TP + p] = val2; }
            else if (col < 150) Wv2T[(b * THP + col - 75) * TP + p] = val2;
            else if (col < 155) Wv2T[(b * THP + col - 75) * TP + p] = 0.0f;
        }
    }
}

// -------- scores -> softmax(i) -> a16[b][j][i] (f16) ------------------------
__global__ __launch_bounds__(256) void score_kernel(
    const float* __restrict__ Wv1, const float* __restrict__ Wv2T,
    const float* __restrict__ vw, half_t* __restrict__ a16)
{
    int tid = threadIdx.x;
    int b  = blockIdx.x >> 7;
    int j0 = (blockIdx.x & 127) * 4;
    __shared__ float wv1j[4 * THP];
    __shared__ float vws[THP];
    __shared__ float sc[4 * TP];

    if (tid < THP) vws[tid] = (tid < TH) ? vw[tid] : 0.0f;
    for (int e = tid; e < 4 * THP; e += 256) {
        int jj = e / THP, k = e - jj * THP;
        wv1j[e] = Wv1[(b * TP + j0 + jj) * THP + k];
    }
    __syncthreads();

    float Csum = 0.0f;
    {
        const float4* c4 = (const float4*)vws;
        for (int kk = 0; kk < 20; ++kk) { float4 c = c4[kk]; Csum += c.x + c.y + c.z + c.w; }
    }

    int i0 = tid, i1 = tid + 256;
    float acc0[4] = {0.f,0.f,0.f,0.f}, acc1[4] = {0.f,0.f,0.f,0.f};
    const float* wvt = Wv2T + b * THP * TP;
#pragma unroll
    for (int kt = 0; kt < 5; ++kt) {
        float r0v[16], r1v[16];
#pragma unroll
        for (int u = 0; u < 16; ++u) {
            const float* colp = wvt + (kt * 16 + u) * TP;
            r0v[u] = colp[i0];
            r1v[u] = colp[i1];
        }
        const float* cp = vws + kt * 16;
#pragma unroll
        for (int jj = 0; jj < 4; ++jj) {
            const float* w1 = wv1j + jj * THP + kt * 16;
            float s0 = 0.f, s1 = 0.f;
#pragma unroll
            for (int u = 0; u < 16; ++u) {
                float cu = cp[u], wu = w1[u];
                s0 += cu * fast_rcp(1.0f + __expf(r0v[u] + wu));
                s1 += cu * fast_rcp(1.0f + __expf(r1v[u] + wu));
            }
            acc0[jj] += s0; acc1[jj] += s1;
        }
    }
#pragma unroll
    for (int jj = 0; jj < 4; ++jj) {
        sc[jj * TP + i0] = Csum - 2.0f * acc0[jj];
        sc[jj * TP + i1] = Csum - 2.0f * acc1[jj];
    }
    __syncthreads();

    {
        int jj = tid >> 6, l = tid & 63;
        float m = -1e30f;
#pragma unroll
        for (int q = 0; q < 8; ++q) m = fmaxf(m, sc[jj * TP + l + q * 64]);
#pragma unroll
        for (int s = 32; s > 0; s >>= 1) m = fmaxf(m, __shfl_xor(m, s));
        float e[8];
        float sum = 0.0f;
#pragma unroll
        for (int q = 0; q < 8; ++q) { e[q] = __expf(sc[jj * TP + l + q * 64] - m); sum += e[q]; }
#pragma unroll
        for (int s = 32; s > 0; s >>= 1) sum += __shfl_xor(sum, s);
        float inv = fast_rcp(sum);
        half_t* arow = a16 + (b * TP + j0 + jj) * TP;
#pragma unroll
        for (int q = 0; q < 8; ++q) arow[l + q * 64] = (half_t)(e[q] * inv);
    }
}

// -------- context via MFMA: c[j,b,d] = sum_i a[b,j,i] * v[i,b,d] ------------
__global__ __launch_bounds__(256) void context_kernel(
    const half_t* __restrict__ a16, const half_t* __restrict__ vT16,
    half_t* __restrict__ g16)
{
    int tid = threadIdx.x;
    int lane = tid & 63, w = tid >> 6;
    int l15 = lane & 15, quad = lane >> 4;
    int b  = blockIdx.x >> 5;
    int mt = blockIdx.x & 31;

    const half_t* arow = a16 + (b * TP + mt * 16 + l15) * TP;
    const half_t* vbase = vT16 + ((b * 256) << 9);

    float4v acc[4];
#pragma unroll
    for (int nti = 0; nti < 4; ++nti) acc[nti] = (float4v){0.f, 0.f, 0.f, 0.f};

#pragma unroll 4
    for (int kt = 0; kt < 16; ++kt) {
        half8v a = *(const half8v*)(arow + kt * 32 + quad * 8);
#pragma unroll
        for (int nti = 0; nti < 4; ++nti) {
            int d = (w * 4 + nti) * 16 + l15;
            half8v bb = *(const half8v*)(vbase + (d << 9) + kt * 32 + quad * 8);
            acc[nti] = __builtin_amdgcn_mfma_f32_16x16x32_f16(a, bb, acc[nti], 0, 0, 0);
        }
    }
#pragma unroll
    for (int nti = 0; nti < 4; ++nti) {
        int d = (w * 4 + nti) * 16 + l15;
#pragma unroll
        for (int r = 0; r < 4; ++r) {
            int j = mt * 16 + quad * 4 + r;
            g16[(j * TB + b) * 512 + 256 + d] = (half_t)acc[nti][r];
        }
    }
}

// -------- MFMA gate (sigmoid(g Wg^T)*g) + GRU input projections -------------
__global__ __launch_bounds__(256, 1) void gatexp_kernel(
    const half_t* __restrict__ g16, const half_t* __restrict__ Wg16B,
    const half_t* __restrict__ Wih16B, const float* __restrict__ bihC,
    float* __restrict__ xpf, float* __restrict__ xpb)
{
    __shared__ half_t gA[32 * 520];      // rows padded to 520 halfs
    int tid = threadIdx.x;
    int r0 = blockIdx.x * 32;
    int lane = tid & 63, w = tid >> 6;
    int l15 = lane & 15, quad = lane >> 4;

    for (int e = tid; e < 2048; e += 256) {
        int row = e >> 6, c8 = e & 63;
        *(half8v*)(gA + row * 520 + c8 * 8) =
            *(const half8v*)(g16 + (r0 + row) * 512 + c8 * 8);
    }
    __syncthreads();

    float4v acc[2][8];
#pragma unroll
    for (int mi = 0; mi < 2; ++mi)
#pragma unroll
        for (int nti = 0; nti < 8; ++nti) acc[mi][nti] = (float4v){0.f, 0.f, 0.f, 0.f};

    for (int kt = 0; kt < 16; ++kt) {
        half8v a0 = *(const half8v*)(gA + l15 * 520 + kt * 32 + quad * 8);
        half8v a1 = *(const half8v*)(gA + (16 + l15) * 520 + kt * 32 + quad * 8);
#pragma unroll
        for (int nti = 0; nti < 8; ++nti) {
            half8v bb = *(const half8v*)(Wg16B + (((w * 8 + nti) * 16 + kt) * 64 + lane) * 8);
            acc[0][nti] = __builtin_amdgcn_mfma_f32_16x16x32_f16(a0, bb, acc[0][nti], 0, 0, 0);
            acc[1][nti] = __builtin_amdgcn_mfma_f32_16x16x32_f16(a1, bb, acc[1][nti], 0, 0, 0);
        }
    }
#pragma unroll
    for (int mi = 0; mi < 2; ++mi)
#pragma unroll
        for (int nti = 0; nti < 8; ++nti) {
            int colg = (w * 8 + nti) * 16 + l15;
#pragma unroll
            for (int r = 0; r < 4; ++r) {
                float gv = (float)gA[(mi * 16 + quad * 4 + r) * 520 + colg];
                acc[mi][nti][r] = fast_sigmoid(acc[mi][nti][r]) * gv;
            }
        }
    __syncthreads();
#pragma unroll
    for (int mi = 0; mi < 2; ++mi)
#pragma unroll
        for (int nti = 0; nti < 8; ++nti) {
            int colg = (w * 8 + nti) * 16 + l15;
#pragma unroll
            for (int r = 0; r < 4; ++r)
                gA[(mi * 16 + quad * 4 + r) * 520 + colg] = (half_t)acc[mi][nti][r];
        }
    __syncthreads();

    float4v c2[2][12];
#pragma unroll
    for (int mi = 0; mi < 2; ++mi)
#pragma unroll
        for (int nt2 = 0; nt2 < 12; ++nt2) {
            float bv = bihC[(w * 12 + nt2) * 16 + l15];
            c2[mi][nt2] = (float4v){bv, bv, bv, bv};
        }

    for (int kt = 0; kt < 16; ++kt) {
        half8v a0 = *(const half8v*)(gA + l15 * 520 + kt * 32 + quad * 8);
        half8v a1 = *(const half8v*)(gA + (16 + l15) * 520 + kt * 32 + quad * 8);
#pragma unroll
        for (int nt2 = 0; nt2 < 12; ++nt2) {
            half8v bb = *(const half8v*)(Wih16B + (((w * 12 + nt2) * 16 + kt) * 64 + lane) * 8);
            c2[0][nt2] = __builtin_amdgcn_mfma_f32_16x16x32_f16(a0, bb, c2[0][nt2], 0, 0, 0);
            c2[1][nt2] = __builtin_amdgcn_mfma_f32_16x16x32_f16(a1, bb, c2[1][nt2], 0, 0, 0);
        }
    }
#pragma unroll
    for (int mi = 0; mi < 2; ++mi)
#pragma unroll
        for (int nt2 = 0; nt2 < 12; ++nt2) {
            int col = (w * 12 + nt2) * 16 + l15;
            float* dst = (col < 384) ? (xpf + col) : (xpb + col - 384);
#pragma unroll
            for (int r = 0; r < 4; ++r)
                dst[(r0 + mi * 16 + quad * 4 + r) * 384] = c2[mi][nt2][r];
        }
}

// ---------------- GRU recurrence, one block per (dir, batch) ----------------
// R10-proven code patterns (H8 union + fdot2h + DPP sums + macro-batched
// global traffic). Structural change: 256 threads (4 waves), thread =
// (o = tid>>1, K-half = tid&1). Same total DS bytes and VALU MACs, but
// 1 wave/SIMD (no intra-SIMD round-robin), half the barrier participants,
// one DPP reduction stage, and epilogue exec-mask 1/2 instead of 1/4.
__global__ __launch_bounds__(256) void gru_kernel(
    const float* __restrict__ xpf, const float* __restrict__ xpb,
    const half_t* __restrict__ whh16,
    const float* __restrict__ bhhf, const float* __restrict__ bhhb,
    float* __restrict__ out)
{
    int tid = threadIdx.x;
    int dir = blockIdx.x >> 3;
    int b   = blockIdx.x & 7;
    const float* xp  = dir ? xpb  : xpf;
    const float* bhh = dir ? bhhb : bhhf;
    const half_t* wbase = whh16 + dir * 3 * TO * TO;

    __shared__ __align__(16) half_t hb[2][TO];

    int o = tid >> 1, hf = tid & 1;

    H8 wr[8], wz[8], wn[8];
    {
        const half8v* pr = (const half8v*)(wbase + (o)          * TO + hf * 64);
        const half8v* pz = (const half8v*)(wbase + (TO + o)     * TO + hf * 64);
        const half8v* pn = (const half8v*)(wbase + (2 * TO + o) * TO + hf * 64);
#pragma unroll
        for (int kk = 0; kk < 8; ++kk) { wr[kk].v8 = pr[kk]; wz[kk].v8 = pz[kk]; wn[kk].v8 = pn[kk]; }
    }

    float br = 0.f, bz = 0.f, bn = 0.f, h = 0.f;
    if (hf == 0) {
        br = bhh[o]; bz = bhh[TO + o]; bn = bhh[2 * TO + o];
    }
    if (tid < TO) hb[0][tid] = (half_t)0.0f;
    __syncthreads();

    float xrv[8], xzv[8], xnv[8], hist[8];

    for (int S = 0; S < TP; S += 8) {
        // batch-issue 24 xp loads for steps S..S+7 (hf==0 lanes)
        if (hf == 0) {
#pragma unroll
            for (int u = 0; u < 8; ++u) {
                int s = S + u;
                int tn = dir ? (TP - 1 - s) : s;
                const float* xpt = xp + (tn * TB + b) * 384;
                xrv[u] = xpt[o]; xzv[u] = xpt[TO + o]; xnv[u] = xpt[2 * TO + o];
            }
        }
#pragma unroll
        for (int u = 0; u < 8; ++u) {
            int s = S + u;
            int cur = s & 1;
            const half8v* h8 = (const half8v*)(&hb[cur][hf * 64]);
            H8 hv[8];
#pragma unroll
            for (int kk = 0; kk < 8; ++kk) hv[kk].v8 = h8[kk];

            float ar = 0.f, az = 0.f, an = 0.f;
#pragma unroll
            for (int kk = 0; kk < 8; ++kk) {
#pragma unroll
                for (int j = 0; j < 4; ++j) {
                    half2v hp = hv[kk].v2[j];
                    ar = fdot2h(wr[kk].v2[j], hp, ar);
                    az = fdot2h(wz[kk].v2[j], hp, az);
                    an = fdot2h(wn[kk].v2[j], hp, an);
                }
            }
            ar = pair_sum_dpp(ar);
            az = pair_sum_dpp(az);
            an = pair_sum_dpp(an);
            if (hf == 0) {
                float r = fast_sigmoid(xrv[u] + ar + br);
                float z = fast_sigmoid(xzv[u] + az + bz);
                float n = fast_tanh(xnv[u] + r * (an + bn));
                h = (1.0f - z) * n + z * h;
                hb[cur ^ 1][o] = (half_t)h;
                hist[u] = h;
            }
            __syncthreads();
        }
        // batch the out-stores (acks amortized over the next macro-step)
        if (hf == 0) {
#pragma unroll
            for (int u = 0; u < 8; ++u) {
                int s = S + u;
                int t = dir ? (TP - 1 - s) : s;
                out[(t * TB + b) * 256 + dir * TO + o] = hist[u];
            }
        }
    }
}

extern "C" void kernel_launch(void* const* d_in, const int* in_sizes, int n_in,
                              void* d_out, int out_size, void* d_ws, size_t ws_size,
                              hipStream_t stream) {
    const float* v    = (const float*)d_in[0];
    const float* Wvp1 = (const float*)d_in[1];
    const float* Wvp2 = (const float*)d_in[2];
    const float* vw   = (const float*)d_in[3];
    const float* Wg   = (const float*)d_in[4];
    const float* wihf = (const float*)d_in[5];
    const float* whhf = (const float*)d_in[6];
    const float* bihf = (const float*)d_in[7];
    const float* bhhf = (const float*)d_in[8];
    const float* wihb = (const float*)d_in[9];
    const float* whhb = (const float*)d_in[10];
    const float* bihb = (const float*)d_in[11];
    const float* bhhb = (const float*)d_in[12];

    float* ws   = (float*)d_ws;
    float* bihC = ws;                    // 768 f32
    float* Wv1  = bihC + 768;            // 8*512*80 = 327680
    float* Wv2T = Wv1 + 327680;          // 8*80*512 = 327680 (transposed)
    float* xpf  = Wv2T + 327680;         // 4096*384 = 1572864
    float* xpb  = xpf + 1572864;         // 1572864
    half_t* g16    = (half_t*)(xpb + 1572864);  // 4096*512   = 2097152 halfs
    half_t* Wg16B  = g16 + 2097152;             // 262144
    half_t* Wih16B = Wg16B + 262144;            // 393216
    half_t* whh16  = Wih16B + 393216;           // 98304
    half_t* v16    = whh16 + 98304;             // 1048576
    half_t* WT16B  = v16 + 1048576;             // 40960
    half_t* vT16   = WT16B + 40960;             // 8*256*512  = 1048576
    half_t* a16    = vT16 + 1048576;            // 8*512*512  = 2097152
    float* out  = (float*)d_out;

    // prep idx total: 1048576+768+262144+393216+98304+40960 = 1843968 = 7203*256
    prep_kernel<<<7203, 256, 0, stream>>>(v, Wvp1, Wvp2, Wg, wihf, wihb, bihf, bihb,
                                          whhf, whhb, bihC, v16, g16,
                                          Wg16B, Wih16B, whh16, WT16B);
    vtrans_kernel<<<256, 256, 0, stream>>>(v, vT16);
    wv12_kernel<<<64, 256, 0, stream>>>(v16, WT16B, Wv1, Wv2T);
    score_kernel<<<1024, 256, 0, stream>>>(Wv1, Wv2T, vw, a16);
    context_kernel<<<256, 256, 0, stream>>>(a16, vT16, g16);
    gatexp_kernel<<<128, 256, 0, stream>>>(g16, Wg16B, Wih16B, bihC, xpf, xpb);
    gru_kernel<<<16, 256, 0, stream>>>(xpf, xpb, whh16, bhhf, bhhb, out);
}

// Round 13
// 440.141 us; speedup vs baseline: 1.7609x; 1.0024x over previous
//
#include <hip/hip_runtime.h>

// Problem constants
#define TP 512   // passage length
#define TB 8     // batch
#define TD 256   // input size
#define TH 75    // attn hidden
#define THP 80   // padded attn hidden (float4-friendly, pads zeroed)
#define TO 128   // GRU hidden

typedef _Float16 half_t;
typedef _Float16 half2v __attribute__((ext_vector_type(2)));
typedef _Float16 half4v __attribute__((ext_vector_type(4)));
typedef _Float16 half8v __attribute__((ext_vector_type(8)));
typedef float    float4v __attribute__((ext_vector_type(4)));

__device__ __forceinline__ float fast_rcp(float x) { return __builtin_amdgcn_rcpf(x); }
__device__ __forceinline__ float fast_tanh(float x) {
    return 1.0f - 2.0f * fast_rcp(1.0f + __expf(2.0f * x));
}
__device__ __forceinline__ float fast_sigmoid(float x) {
    return fast_rcp(1.0f + __expf(-x));
}
__device__ __forceinline__ float fdot2h(half2v a, half2v b, float c) {
#if __has_builtin(__builtin_amdgcn_fdot2)
    return __builtin_amdgcn_fdot2(a, b, c, false);
#else
    return c + (float)a[0] * (float)b[0] + (float)a[1] * (float)b[1];
#endif
}
// aliasing-safe half2 extraction from half8v: sub-register, no punning
#define EXT2(v, j) __builtin_shufflevector((v), (v), 2*(j), 2*(j)+1)
// 3-gate dot over one 8-half chunk (4 half2 pairs per gate)
__device__ __forceinline__ void dot3_h8(half8v wr, half8v wz, half8v wn, half8v h,
                                        float& ar, float& az, float& an) {
    half2v h0 = EXT2(h, 0), h1 = EXT2(h, 1), h2 = EXT2(h, 2), h3 = EXT2(h, 3);
    ar = fdot2h(EXT2(wr, 0), h0, ar);
    az = fdot2h(EXT2(wz, 0), h0, az);
    an = fdot2h(EXT2(wn, 0), h0, an);
    ar = fdot2h(EXT2(wr, 1), h1, ar);
    az = fdot2h(EXT2(wz, 1), h1, az);
    an = fdot2h(EXT2(wn, 1), h1, an);
    ar = fdot2h(EXT2(wr, 2), h2, ar);
    az = fdot2h(EXT2(wz, 2), h2, az);
    an = fdot2h(EXT2(wn, 2), h2, an);
    ar = fdot2h(EXT2(wr, 3), h3, ar);
    az = fdot2h(EXT2(wz, 3), h3, az);
    an = fdot2h(EXT2(wn, 3), h3, an);
}
// adjacent-lane (xor-1) butterfly sum via DPP quad_perm [1,0,3,2] (VALU pipe).
__device__ __forceinline__ float pair_sum_dpp(float v) {
    int i1 = __builtin_amdgcn_update_dpp(0, __builtin_bit_cast(int, v), 0xB1, 0xF, 0xF, true);
    return v + __builtin_bit_cast(float, i1);
}

// ---------------- prep: f16 casts, B-frag swizzles, whh16 -------------------
// B-frag layout (mfma_f32_16x16x32_f16): [nt][kt][lane][j] halfs with
// B[k = kt*32 + (lane>>4)*8 + j][n = nt*16 + (lane&15)]  (verified R5/R6).
__global__ __launch_bounds__(256) void prep_kernel(
    const float* __restrict__ v,
    const float* __restrict__ Wvp1, const float* __restrict__ Wvp2,
    const float* __restrict__ Wg,   const float* __restrict__ wihf,
    const float* __restrict__ wihb, const float* __restrict__ bihf,
    const float* __restrict__ bihb, const float* __restrict__ whhf,
    const float* __restrict__ whhb,
    float* __restrict__ bihC,
    half_t* __restrict__ v16, half_t* __restrict__ g16,
    half_t* __restrict__ Wg16B, half_t* __restrict__ Wih16B,
    half_t* __restrict__ whh16, half_t* __restrict__ WT16B)
{
    int idx = blockIdx.x * 256 + threadIdx.x;
    if (idx < 1048576) {                        // v cast (coalesced)
        half_t val = (half_t)v[idx];
        v16[idx] = val;                          // [p*8+b][d]
        int row = idx >> 8, d = idx & 255;       // row = p*8+b
        g16[row * 512 + d] = val;                // g first half = v
        return;
    }
    idx -= 1048576;
    if (idx < 768) { bihC[idx] = (idx < 384) ? bihf[idx] : bihb[idx - 384]; return; }
    idx -= 768;
    if (idx < 262144) {                         // Wg16B (nt 0..31)
        int j = idx & 7, lane = (idx >> 3) & 63, kt = (idx >> 9) & 15, nt = idx >> 13;
        int o = nt * 16 + (lane & 15);
        int k = kt * 32 + ((lane >> 4) << 3) + j;
        Wg16B[idx] = (half_t)Wg[o * 512 + k];
        return;
    }
    idx -= 262144;
    if (idx < 393216) {                         // Wih16B (nt 0..47, o<384 fwd)
        int j = idx & 7, lane = (idx >> 3) & 63, kt = (idx >> 9) & 15, nt = idx >> 13;
        int o = nt * 16 + (lane & 15);
        int k = kt * 32 + ((lane >> 4) << 3) + j;
        Wih16B[idx] = (half_t)((o < 384) ? wihf[o * 512 + k] : wihb[(o - 384) * 512 + k]);
        return;
    }
    idx -= 393216;
    if (idx < 98304) {                          // whh16[dir][(g*128+o)*128+k]
        int d = idx / 49152, i = idx - d * 49152;
        whh16[idx] = (half_t)(d ? whhb[i] : whhf[i]);
        return;
    }
    idx -= 98304;
    if (idx < 40960) {                          // WT16B (nt 0..9): [Wvp1;Wvp2]
        int j = idx & 7, lane = (idx >> 3) & 63, kt = (idx >> 9) & 7, nt = idx >> 12;
        int o = nt * 16 + (lane & 15);
        int k = kt * 32 + ((lane >> 4) << 3) + j;
        float vv = 0.0f;
        if (o < 75)       vv = Wvp1[o * 256 + k];
        else if (o < 150) vv = Wvp2[(o - 75) * 256 + k];
        WT16B[idx] = (half_t)vv;
    }
}

// ---------------- vT16[b][d][p] tiled transpose (coalesced R/W) -------------
__global__ __launch_bounds__(256) void vtrans_kernel(
    const float* __restrict__ v, half_t* __restrict__ vT16)
{
    __shared__ half_t lt[64 * 66];   // [d_local][p_local], stride 66
    int t = threadIdx.x;
    int b  = blockIdx.x >> 5;
    int pt = (blockIdx.x >> 2) & 7;
    int dt = blockIdx.x & 3;

    {
        int pl = t >> 2, dseg = (t & 3) * 16;
        const float4* src = (const float4*)(v + (((pt * 64 + pl) * 8 + b) << 8) + dt * 64 + dseg);
        float4 f0 = src[0], f1 = src[1], f2 = src[2], f3 = src[3];
        half_t hv[16] = {
            (half_t)f0.x,(half_t)f0.y,(half_t)f0.z,(half_t)f0.w,
            (half_t)f1.x,(half_t)f1.y,(half_t)f1.z,(half_t)f1.w,
            (half_t)f2.x,(half_t)f2.y,(half_t)f2.z,(half_t)f2.w,
            (half_t)f3.x,(half_t)f3.y,(half_t)f3.z,(half_t)f3.w };
#pragma unroll
        for (int u = 0; u < 16; ++u) lt[(dseg + u) * 66 + pl] = hv[u];
    }
    __syncthreads();
    {
        int dl = t >> 2, pseg = (t & 3) * 16;
        half8v h0 = *(const half8v*)(lt + dl * 66 + pseg);
        half8v h1 = *(const half8v*)(lt + dl * 66 + pseg + 8);
        half8v* dst = (half8v*)(vT16 + ((b * 256 + dt * 64 + dl) << 9) + pt * 64 + pseg);
        dst[0] = h0; dst[1] = h1;
    }
}

// ---------------- Wv1/Wv2T via MFMA: [4096,160] = v16 @ WT16B ---------------
__global__ __launch_bounds__(256) void wv12_kernel(
    const half_t* __restrict__ v16, const half_t* __restrict__ WT16B,
    float* __restrict__ Wv1, float* __restrict__ Wv2T)
{
    int tid = threadIdx.x;
    int lane = tid & 63, w = tid >> 6;
    int l15 = lane & 15, quad = lane >> 4;
    int r0 = blockIdx.x * 64 + w * 16;

    float4v acc[10];
#pragma unroll
    for (int nt = 0; nt < 10; ++nt) acc[nt] = (float4v){0.f, 0.f, 0.f, 0.f};

#pragma unroll
    for (int kt = 0; kt < 8; ++kt) {
        half8v a = *(const half8v*)(v16 + (r0 + l15) * 256 + kt * 32 + quad * 8);
#pragma unroll
        for (int nt = 0; nt < 10; ++nt) {
            half8v b = *(const half8v*)(WT16B + ((nt * 8 + kt) * 64 + lane) * 8);
            acc[nt] = __builtin_amdgcn_mfma_f32_16x16x32_f16(a, b, acc[nt], 0, 0, 0);
        }
    }
#pragma unroll
    for (int nt = 0; nt < 10; ++nt) {
        int col = nt * 16 + l15;
#pragma unroll
        for (int r = 0; r < 4; ++r) {
            int row = r0 + quad * 4 + r;
            int p = row >> 3, b = row & 7;
            int ob = (b * TP + p) * THP;
            float val2 = 2.0f * acc[nt][r];
            if (col < 75)       Wv1[ob + col] = val2;
            else if (col < 80)  { Wv1[ob + col] = 0.0f;
                                  Wv2T[(b * THP + col - 75) * TP + p] = val2; }
            else if (col < 150) Wv2T[(b * THP + col - 75) * TP + p] = val2;
            else if (col < 155) Wv2T[(b * THP + col - 75) * TP + p] = 0.0f;
        }
    }
}

// -------- scores -> softmax(i) -> a16[b][j][i] (f16) ------------------------
__global__ __launch_bounds__(256) void score_kernel(
    const float* __restrict__ Wv1, const float* __restrict__ Wv2T,
    const float* __restrict__ vw, half_t* __restrict__ a16)
{
    int tid = threadIdx.x;
    int b  = blockIdx.x >> 7;
    int j0 = (blockIdx.x & 127) * 4;
    __shared__ float wv1j[4 * THP];
    __shared__ float vws[THP];
    __shared__ float sc[4 * TP];

    if (tid < THP) vws[tid] = (tid < TH) ? vw[tid] : 0.0f;
    for (int e = tid; e < 4 * THP; e += 256) {
        int jj = e / THP, k = e - jj * THP;
        wv1j[e] = Wv1[(b * TP + j0 + jj) * THP + k];
    }
    __syncthreads();

    float Csum = 0.0f;
    {
        const float4* c4 = (const float4*)vws;
        for (int kk = 0; kk < 20; ++kk) { float4 c = c4[kk]; Csum += c.x + c.y + c.z + c.w; }
    }

    int i0 = tid, i1 = tid + 256;
    float acc0[4] = {0.f,0.f,0.f,0.f}, acc1[4] = {0.f,0.f,0.f,0.f};
    const float* wvt = Wv2T + b * THP * TP;
#pragma unroll
    for (int kt = 0; kt < 5; ++kt) {
        float r0v[16], r1v[16];
#pragma unroll
        for (int u = 0; u < 16; ++u) {
            const float* colp = wvt + (kt * 16 + u) * TP;
            r0v[u] = colp[i0];
            r1v[u] = colp[i1];
        }
        const float* cp = vws + kt * 16;
#pragma unroll
        for (int jj = 0; jj < 4; ++jj) {
            const float* w1 = wv1j + jj * THP + kt * 16;
            float s0 = 0.f, s1 = 0.f;
#pragma unroll
            for (int u = 0; u < 16; ++u) {
                float cu = cp[u], wu = w1[u];
                s0 += cu * fast_rcp(1.0f + __expf(r0v[u] + wu));
                s1 += cu * fast_rcp(1.0f + __expf(r1v[u] + wu));
            }
            acc0[jj] += s0; acc1[jj] += s1;
        }
    }
#pragma unroll
    for (int jj = 0; jj < 4; ++jj) {
        sc[jj * TP + i0] = Csum - 2.0f * acc0[jj];
        sc[jj * TP + i1] = Csum - 2.0f * acc1[jj];
    }
    __syncthreads();

    {
        int jj = tid >> 6, l = tid & 63;
        float m = -1e30f;
#pragma unroll
        for (int q = 0; q < 8; ++q) m = fmaxf(m, sc[jj * TP + l + q * 64]);
#pragma unroll
        for (int s = 32; s > 0; s >>= 1) m = fmaxf(m, __shfl_xor(m, s));
        float e[8];
        float sum = 0.0f;
#pragma unroll
        for (int q = 0; q < 8; ++q) { e[q] = __expf(sc[jj * TP + l + q * 64] - m); sum += e[q]; }
#pragma unroll
        for (int s = 32; s > 0; s >>= 1) sum += __shfl_xor(sum, s);
        float inv = fast_rcp(sum);
        half_t* arow = a16 + (b * TP + j0 + jj) * TP;
#pragma unroll
        for (int q = 0; q < 8; ++q) arow[l + q * 64] = (half_t)(e[q] * inv);
    }
}

// -------- context via MFMA: c[j,b,d] = sum_i a[b,j,i] * v[i,b,d] ------------
__global__ __launch_bounds__(256) void context_kernel(
    const half_t* __restrict__ a16, const half_t* __restrict__ vT16,
    half_t* __restrict__ g16)
{
    int tid = threadIdx.x;
    int lane = tid & 63, w = tid >> 6;
    int l15 = lane & 15, quad = lane >> 4;
    int b  = blockIdx.x >> 5;
    int mt = blockIdx.x & 31;

    const half_t* arow = a16 + (b * TP + mt * 16 + l15) * TP;
    const half_t* vbase = vT16 + ((b * 256) << 9);

    float4v acc[4];
#pragma unroll
    for (int nti = 0; nti < 4; ++nti) acc[nti] = (float4v){0.f, 0.f, 0.f, 0.f};

#pragma unroll 4
    for (int kt = 0; kt < 16; ++kt) {
        half8v a = *(const half8v*)(arow + kt * 32 + quad * 8);
#pragma unroll
        for (int nti = 0; nti < 4; ++nti) {
            int d = (w * 4 + nti) * 16 + l15;
            half8v bb = *(const half8v*)(vbase + (d << 9) + kt * 32 + quad * 8);
            acc[nti] = __builtin_amdgcn_mfma_f32_16x16x32_f16(a, bb, acc[nti], 0, 0, 0);
        }
    }
#pragma unroll
    for (int nti = 0; nti < 4; ++nti) {
        int d = (w * 4 + nti) * 16 + l15;
#pragma unroll
        for (int r = 0; r < 4; ++r) {
            int j = mt * 16 + quad * 4 + r;
            g16[(j * TB + b) * 512 + 256 + d] = (half_t)acc[nti][r];
        }
    }
}

// -------- MFMA gate (sigmoid(g Wg^T)*g) + GRU input projections -------------
__global__ __launch_bounds__(256, 1) void gatexp_kernel(
    const half_t* __restrict__ g16, const half_t* __restrict__ Wg16B,
    const half_t* __restrict__ Wih16B, const float* __restrict__ bihC,
    float* __restrict__ xpf, float* __restrict__ xpb)
{
    __shared__ half_t gA[32 * 520];      // rows padded to 520 halfs
    int tid = threadIdx.x;
    int r0 = blockIdx.x * 32;
    int lane = tid & 63, w = tid >> 6;
    int l15 = lane & 15, quad = lane >> 4;

    for (int e = tid; e < 2048; e += 256) {
        int row = e >> 6, c8 = e & 63;
        *(half8v*)(gA + row * 520 + c8 * 8) =
            *(const half8v*)(g16 + (r0 + row) * 512 + c8 * 8);
    }
    __syncthreads();

    float4v acc[2][8];
#pragma unroll
    for (int mi = 0; mi < 2; ++mi)
#pragma unroll
        for (int nti = 0; nti < 8; ++nti) acc[mi][nti] = (float4v){0.f, 0.f, 0.f, 0.f};

    for (int kt = 0; kt < 16; ++kt) {
        half8v a0 = *(const half8v*)(gA + l15 * 520 + kt * 32 + quad * 8);
        half8v a1 = *(const half8v*)(gA + (16 + l15) * 520 + kt * 32 + quad * 8);
#pragma unroll
        for (int nti = 0; nti < 8; ++nti) {
            half8v bb = *(const half8v*)(Wg16B + (((w * 8 + nti) * 16 + kt) * 64 + lane) * 8);
            acc[0][nti] = __builtin_amdgcn_mfma_f32_16x16x32_f16(a0, bb, acc[0][nti], 0, 0, 0);
            acc[1][nti] = __builtin_amdgcn_mfma_f32_16x16x32_f16(a1, bb, acc[1][nti], 0, 0, 0);
        }
    }
#pragma unroll
    for (int mi = 0; mi < 2; ++mi)
#pragma unroll
        for (int nti = 0; nti < 8; ++nti) {
            int colg = (w * 8 + nti) * 16 + l15;
#pragma unroll
            for (int r = 0; r < 4; ++r) {
                float gv = (float)gA[(mi * 16 + quad * 4 + r) * 520 + colg];
                acc[mi][nti][r] = fast_sigmoid(acc[mi][nti][r]) * gv;
            }
        }
    __syncthreads();
#pragma unroll
    for (int mi = 0; mi < 2; ++mi)
#pragma unroll
        for (int nti = 0; nti < 8; ++nti) {
            int colg = (w * 8 + nti) * 16 + l15;
#pragma unroll
            for (int r = 0; r < 4; ++r)
                gA[(mi * 16 + quad * 4 + r) * 520 + colg] = (half_t)acc[mi][nti][r];
        }
    __syncthreads();

    float4v c2[2][12];
#pragma unroll
    for (int mi = 0; mi < 2; ++mi)
#pragma unroll
        for (int nt2 = 0; nt2 < 12; ++nt2) {
            float bv = bihC[(w * 12 + nt2) * 16 + l15];
            c2[mi][nt2] = (float4v){bv, bv, bv, bv};
        }

    for (int kt = 0; kt < 16; ++kt) {
        half8v a0 = *(const half8v*)(gA + l15 * 520 + kt * 32 + quad * 8);
        half8v a1 = *(const half8v*)(gA + (16 + l15) * 520 + kt * 32 + quad * 8);
#pragma unroll
        for (int nt2 = 0; nt2 < 12; ++nt2) {
            half8v bb = *(const half8v*)(Wih16B + (((w * 12 + nt2) * 16 + kt) * 64 + lane) * 8);
            c2[0][nt2] = __builtin_amdgcn_mfma_f32_16x16x32_f16(a0, bb, c2[0][nt2], 0, 0, 0);
            c2[1][nt2] = __builtin_amdgcn_mfma_f32_16x16x32_f16(a1, bb, c2[1][nt2], 0, 0, 0);
        }
    }
#pragma unroll
    for (int mi = 0; mi < 2; ++mi)
#pragma unroll
        for (int nt2 = 0; nt2 < 12; ++nt2) {
            int col = (w * 12 + nt2) * 16 + l15;
            float* dst = (col < 384) ? (xpf + col) : (xpb + col - 384);
#pragma unroll
            for (int r = 0; r < 4; ++r)
                dst[(r0 + mi * 16 + quad * 4 + r) * 384] = c2[mi][nt2][r];
        }
}

// ---------------- GRU recurrence, one block per (dir, batch) ----------------
// R12 structure (237 us): 256 threads (4 waves), thread = (o = tid>>1,
// K-half = tid&1), macro-batched global traffic, DPP pair-sum. Codegen fix:
// half8v loads + __builtin_shufflevector half2 extraction (sub-register,
// aliasing-safe) replacing the H8 union whose SROA materialized ~120 extra
// extract moves per step (VALUBusy evidence: 261 vs ~135 expected instrs).
__global__ __launch_bounds__(256) void gru_kernel(
    const float* __restrict__ xpf, const float* __restrict__ xpb,
    const half_t* __restrict__ whh16,
    const float* __restrict__ bhhf, const float* __restrict__ bhhb,
    float* __restrict__ out)
{
    int tid = threadIdx.x;
    int dir = blockIdx.x >> 3;
    int b   = blockIdx.x & 7;
    const float* xp  = dir ? xpb  : xpf;
    const float* bhh = dir ? bhhb : bhhf;
    const half_t* wbase = whh16 + dir * 3 * TO * TO;

    __shared__ __align__(16) half_t hb[2][TO];

    int o = tid >> 1, hf = tid & 1;

    half8v wr[8], wz[8], wn[8];
    {
        const half8v* pr = (const half8v*)(wbase + (o)          * TO + hf * 64);
        const half8v* pz = (const half8v*)(wbase + (TO + o)     * TO + hf * 64);
        const half8v* pn = (const half8v*)(wbase + (2 * TO + o) * TO + hf * 64);
#pragma unroll
        for (int kk = 0; kk < 8; ++kk) { wr[kk] = pr[kk]; wz[kk] = pz[kk]; wn[kk] = pn[kk]; }
    }

    float br = 0.f, bz = 0.f, bn = 0.f, h = 0.f;
    if (hf == 0) {
        br = bhh[o]; bz = bhh[TO + o]; bn = bhh[2 * TO + o];
    }
    if (tid < TO) hb[0][tid] = (half_t)0.0f;
    __syncthreads();

    float xrv[8], xzv[8], xnv[8], hist[8];

    for (int S = 0; S < TP; S += 8) {
        // batch-issue 24 xp loads for steps S..S+7 (hf==0 lanes)
        if (hf == 0) {
#pragma unroll
            for (int u = 0; u < 8; ++u) {
                int s = S + u;
                int tn = dir ? (TP - 1 - s) : s;
                const float* xpt = xp + (tn * TB + b) * 384;
                xrv[u] = xpt[o]; xzv[u] = xpt[TO + o]; xnv[u] = xpt[2 * TO + o];
            }
        }
#pragma unroll
        for (int u = 0; u < 8; ++u) {
            int s = S + u;
            int cur = s & 1;
            const half8v* h8 = (const half8v*)(&hb[cur][hf * 64]);
            half8v hv0 = h8[0], hv1 = h8[1], hv2 = h8[2], hv3 = h8[3];
            half8v hv4 = h8[4], hv5 = h8[5], hv6 = h8[6], hv7 = h8[7];

            float ar = 0.f, az = 0.f, an = 0.f;
            dot3_h8(wr[0], wz[0], wn[0], hv0, ar, az, an);
            dot3_h8(wr[1], wz[1], wn[1], hv1, ar, az, an);
            dot3_h8(wr[2], wz[2], wn[2], hv2, ar, az, an);
            dot3_h8(wr[3], wz[3], wn[3], hv3, ar, az, an);
            dot3_h8(wr[4], wz[4], wn[4], hv4, ar, az, an);
            dot3_h8(wr[5], wz[5], wn[5], hv5, ar, az, an);
            dot3_h8(wr[6], wz[6], wn[6], hv6, ar, az, an);
            dot3_h8(wr[7], wz[7], wn[7], hv7, ar, az, an);

            ar = pair_sum_dpp(ar);
            az = pair_sum_dpp(az);
            an = pair_sum_dpp(an);
            if (hf == 0) {
                float r = fast_sigmoid(xrv[u] + ar + br);
                float z = fast_sigmoid(xzv[u] + az + bz);
                float n = fast_tanh(xnv[u] + r * (an + bn));
                h = (1.0f - z) * n + z * h;
                hb[cur ^ 1][o] = (half_t)h;
                hist[u] = h;
            }
            __syncthreads();
        }
        // batch the out-stores (acks amortized over the next macro-step)
        if (hf == 0) {
#pragma unroll
            for (int u = 0; u < 8; ++u) {
                int s = S + u;
                int t = dir ? (TP - 1 - s) : s;
                out[(t * TB + b) * 256 + dir * TO + o] = hist[u];
            }
        }
    }
}

extern "C" void kernel_launch(void* const* d_in, const int* in_sizes, int n_in,
                              void* d_out, int out_size, void* d_ws, size_t ws_size,
                              hipStream_t stream) {
    const float* v    = (const float*)d_in[0];
    const float* Wvp1 = (const float*)d_in[1];
    const float* Wvp2 = (const float*)d_in[2];
    const float* vw   = (const float*)d_in[3];
    const float* Wg   = (const float*)d_in[4];
    const float* wihf = (const float*)d_in[5];
    const float* whhf = (const float*)d_in[6];
    const float* bihf = (const float*)d_in[7];
    const float* bhhf = (const float*)d_in[8];
    const float* wihb = (const float*)d_in[9];
    const float* whhb = (const float*)d_in[10];
    const float* bihb = (const float*)d_in[11];
    const float* bhhb = (const float*)d_in[12];

    float* ws   = (float*)d_ws;
    float* bihC = ws;                    // 768 f32
    float* Wv1  = bihC + 768;            // 8*512*80 = 327680
    float* Wv2T = Wv1 + 327680;          // 8*80*512 = 327680 (transposed)
    float* xpf  = Wv2T + 327680;         // 4096*384 = 1572864
    float* xpb  = xpf + 1572864;         // 1572864
    half_t* g16    = (half_t*)(xpb + 1572864);  // 4096*512   = 2097152 halfs
    half_t* Wg16B  = g16 + 2097152;             // 262144
    half_t* Wih16B = Wg16B + 262144;            // 393216
    half_t* whh16  = Wih16B + 393216;           // 98304
    half_t* v16    = whh16 + 98304;             // 1048576
    half_t* WT16B  = v16 + 1048576;             // 40960
    half_t* vT16   = WT16B + 40960;             // 8*256*512  = 1048576
    half_t* a16    = vT16 + 1048576;            // 8*512*512  = 2097152
    float* out  = (float*)d_out;

    // prep idx total: 1048576+768+262144+393216+98304+40960 = 1843968 = 7203*256
    prep_kernel<<<7203, 256, 0, stream>>>(v, Wvp1, Wvp2, Wg, wihf, wihb, bihf, bihb,
                                          whhf, whhb, bihC, v16, g16,
                                          Wg16B, Wih16B, whh16, WT16B);
    vtrans_kernel<<<256, 256, 0, stream>>>(v, vT16);
    wv12_kernel<<<64, 256, 0, stream>>>(v16, WT16B, Wv1, Wv2T);
    score_kernel<<<1024, 256, 0, stream>>>(Wv1, Wv2T, vw, a16);
    context_kernel<<<256, 256, 0, stream>>>(a16, vT16, g16);
    gatexp_kernel<<<128, 256, 0, stream>>>(g16, Wg16B, Wih16B, bihC, xpf, xpb);
    gru_kernel<<<16, 256, 0, stream>>>(xpf, xpb, whh16, bhhf, bhhb, out);
}